// Round 22
// baseline (4050.356 us; speedup 1.0000x reference)
//
#include <hip/hip_runtime.h>

// ===== BDH forward on MI355X — R22: g2 row-pair 256x384 tiles + g1/g4a dbuf =====
// R21 (3022us): g2 staging-traffic-bound (7.7 TB/s L2/L3). R22: g2 blocks do
// 256x384 (A-pair x 3 B-panels): 5 tiles/K-step for 2x work (bytes/output
// x0.625), grid 216 = 8x27 exact XCD chunk, 160KB dbuf, acc[4][12]. g1/g4a
// get 64KB dbuf (g4b pattern). Math per output element identical.

typedef unsigned short u16;
typedef unsigned int   u32;
typedef __attribute__((ext_vector_type(8))) short bf8;
typedef __attribute__((ext_vector_type(4))) float f4;

#define T_  2048
#define D_  256
#define NH_ 4
#define NN_ 4096
#define NLAYER 6

// per-batch strides (elements)
#define XB_E   524288u
#define QR_E   33554432u
#define QR_U32 16777216u
#define SP_U32 4456448u
#define SP_F   4456448u
#define YKV_F  2097152u
#define YKH_E  2097152u

// ---- workspace layout (bytes) ----
#define CSA_OFF  ((size_t)0)
#define CSB_OFF  (CSA_OFF  + 262144)
#define ETH_OFF  (CSB_OFF  + 2097152)
#define EVH_OFF  (ETH_OFF  + 8388608)
#define DTH_OFF  (EVH_OFF  + 8388608)
#define LMH_OFF  (DTH_OFF  + 8388608)
#define LML_OFF  (LMH_OFF  + 131072)
#define X_OFF    (LML_OFF  + 131072)
#define XBH_OFF  (X_OFF    + 4194304)
#define XBL_OFF  (XBH_OFF  + 2097152)
#define XBTH_OFF (XBL_OFF  + 2097152)
#define QRH_OFF  (XBTH_OFF + 2097152)
#define SH_OFF   (QRH_OFF  + 134217728)
#define YKV_OFF  (SH_OFF   + 35651584)
#define YKH_OFF  (YKV_OFF  + 16777216)
#define WS_NEED  (YKH_OFF  + 8388608)

// ---------- helpers ----------
__device__ __forceinline__ u16 f2b(float f) {
  u32 u = __builtin_bit_cast(u32, f);
  u32 r = u + 0x7fffu + ((u >> 16) & 1u);
  return (u16)(r >> 16);
}
__device__ __forceinline__ float b2f(u16 h) {
  u32 u = ((u32)h) << 16;
  return __builtin_bit_cast(float, u);
}
__device__ __forceinline__ float wsum(float v) {
#pragma unroll
  for (int o = 32; o; o >>= 1) v += __shfl_xor(v, o, 64);
  return v;
}
__device__ __forceinline__ float2 trig_ct(const float2* csA, const float2* csB, int t, int pp) {
  float2 a = csA[(t >> 7) * 2048 + pp];
  float2 b = csB[(t & 127) * 2048 + pp];
  return make_float2(a.x * b.x - a.y * b.y, a.x * b.y + a.y * b.x);
}
__device__ __forceinline__ void gld16(const u16* g, short* l) {
  __builtin_amdgcn_global_load_lds(
      (const __attribute__((address_space(1))) u32*)g,
      (__attribute__((address_space(3))) u32*)l, 16, 0, 0);
}
__device__ __forceinline__ void stage_t(const u16* g, int lda, short* s, int wid, int lane) {
  int r8 = lane >> 3;
  int c8 = ((lane & 7) ^ r8) * 8;
#pragma unroll
  for (int j = 0; j < 4; ++j) {
    int row = wid * 32 + j * 8;
    gld16(g + (size_t)(row + r8) * lda + c8, s + row * 64);
  }
}
__device__ __forceinline__ void stage_t8(const u16* g, int lda, short* s, int wid, int lane) {
  int r8 = lane >> 3;
  int c8 = ((lane & 7) ^ r8) * 8;
#pragma unroll
  for (int j = 0; j < 2; ++j) {
    int row = wid * 16 + j * 8;
    gld16(g + (size_t)(row + r8) * lda + c8, s + row * 64);
  }
}
// 3-term split: 96 MFMA — g5 only
__device__ __forceinline__ void mma64x3(const short* AsH, const short* AsL, const short* BsH,
                                        const short* BsL, int wr, int wc, int lane,
                                        f4 acc[4][4]) {
  int r15 = lane & 15, hi = lane >> 4;
  int sw = (r15 & 7) << 3;
#pragma unroll
  for (int kk = 0; kk < 2; ++kk) {
    int ko = (kk * 32 + hi * 8) ^ sw;
    bf8 ah[4], al[4], bh[4], bl[4];
#pragma unroll
    for (int m = 0; m < 4; ++m) {
      int off = (wr * 64 + m * 16 + r15) * 64 + ko;
      ah[m] = *(const bf8*)(AsH + off);
      al[m] = *(const bf8*)(AsL + off);
    }
#pragma unroll
    for (int n = 0; n < 4; ++n) {
      int off = (wc * 64 + n * 16 + r15) * 64 + ko;
      bh[n] = *(const bf8*)(BsH + off);
      bl[n] = *(const bf8*)(BsL + off);
    }
#pragma unroll
    for (int m = 0; m < 4; ++m)
#pragma unroll
      for (int n = 0; n < 4; ++n) {
        acc[m][n] = __builtin_amdgcn_mfma_f32_16x16x32_bf16(ah[m], bh[n], acc[m][n], 0, 0, 0);
        acc[m][n] = __builtin_amdgcn_mfma_f32_16x16x32_bf16(al[m], bh[n], acc[m][n], 0, 0, 0);
        acc[m][n] = __builtin_amdgcn_mfma_f32_16x16x32_bf16(ah[m], bl[n], acc[m][n], 0, 0, 0);
      }
  }
}
// 1-term: 32 MFMA — g1/g3/g4a/g4b
__device__ __forceinline__ void mma64x1(const short* AsH, const short* BsH,
                                        int wr, int wc, int lane, f4 acc[4][4]) {
  int r15 = lane & 15, hi = lane >> 4;
  int sw = (r15 & 7) << 3;
#pragma unroll
  for (int kk = 0; kk < 2; ++kk) {
    int ko = (kk * 32 + hi * 8) ^ sw;
    bf8 ah[4], bh[4];
#pragma unroll
    for (int m = 0; m < 4; ++m)
      ah[m] = *(const bf8*)(AsH + (wr * 64 + m * 16 + r15) * 64 + ko);
#pragma unroll
    for (int n = 0; n < 4; ++n)
      bh[n] = *(const bf8*)(BsH + (wc * 64 + n * 16 + r15) * 64 + ko);
#pragma unroll
    for (int m = 0; m < 4; ++m)
#pragma unroll
      for (int n = 0; n < 4; ++n)
        acc[m][n] = __builtin_amdgcn_mfma_f32_16x16x32_bf16(ah[m], bh[n], acc[m][n], 0, 0, 0);
  }
}
__device__ __forceinline__ void acc_zero(f4 acc[4][4]) {
#pragma unroll
  for (int m = 0; m < 4; ++m)
#pragma unroll
    for (int n = 0; n < 4; ++n)
#pragma unroll
      for (int j = 0; j < 4; ++j) acc[m][n][j] = 0.0f;
}
__device__ __forceinline__ void acc_store_f32(float* F, f4 acc[4][4], int wr, int wc, int lane,
                                              bool relu) {
  int r15 = lane & 15, q = lane >> 4;
#pragma unroll
  for (int m = 0; m < 4; ++m)
#pragma unroll
    for (int n = 0; n < 4; ++n)
#pragma unroll
      for (int j = 0; j < 4; ++j) {
        float v = acc[m][n][j];
        if (relu) v = fmaxf(v, 0.0f);
        F[(wr * 64 + m * 16 + q * 4 + j) * 128 + wc * 64 + n * 16 + r15] = v;
      }
}
__device__ __forceinline__ void acc_store_half(float* F, f4 acc[4][4], int pass, int wr, int wc,
                                               int lane, bool relu) {
  if (wr != pass) return;
  int r15 = lane & 15, q = lane >> 4;
#pragma unroll
  for (int m = 0; m < 4; ++m)
#pragma unroll
    for (int n = 0; n < 4; ++n)
#pragma unroll
      for (int j = 0; j < 4; ++j) {
        float v = acc[m][n][j];
        if (relu) v = fmaxf(v, 0.0f);
        F[(m * 16 + q * 4 + j) * 128 + wc * 64 + n * 16 + r15] = v;
      }
}

// ---------- prep kernels ----------
__global__ __launch_bounds__(256) void k_costab(float2* csA, float2* csB) {
  int id = blockIdx.x * 256 + threadIdx.x;
  int r = id >> 11, p = id & 2047;
  double freq = exp2(-(double)p / 128.0) * 0.15915494309189533577;
  int t = (r < 16) ? (r * 128) : (r - 16);
  double ph = fmod((double)t * freq, 1.0);
  double ang = ph * 6.2831853071795864769;
  float2 v = make_float2((float)cos(ang), (float)sin(ang));
  if (r < 16) csA[r * 2048 + p] = v;
  else        csB[(r - 16) * 2048 + p] = v;
}

__global__ __launch_bounds__(256) void k_tcast1(const float* __restrict__ in,
                                                u16* __restrict__ outH, int R, int C) {
  __shared__ float tl[32][33];
  size_t bo = (size_t)blockIdx.z * R * C;
  int tx = threadIdx.x, ty = threadIdx.y;
  int c = blockIdx.x * 32 + tx, r0 = blockIdx.y * 32 + ty;
#pragma unroll
  for (int k = 0; k < 32; k += 8) tl[ty + k][tx] = in[bo + (size_t)(r0 + k) * C + c];
  __syncthreads();
  int rr = blockIdx.y * 32 + tx, cc0 = blockIdx.x * 32 + ty;
#pragma unroll
  for (int k = 0; k < 32; k += 8) outH[bo + (size_t)(cc0 + k) * R + rr] = f2b(tl[tx][ty + k]);
}

__global__ __launch_bounds__(256) void k_tcast2(const float* __restrict__ in,
                                                u16* __restrict__ outH, u16* __restrict__ outL,
                                                int R, int C) {
  __shared__ float tl[32][33];
  int tx = threadIdx.x, ty = threadIdx.y;
  int c = blockIdx.x * 32 + tx, r0 = blockIdx.y * 32 + ty;
#pragma unroll
  for (int k = 0; k < 32; k += 8) tl[ty + k][tx] = in[(size_t)(r0 + k) * C + c];
  __syncthreads();
  int rr = blockIdx.y * 32 + tx, cc0 = blockIdx.x * 32 + ty;
#pragma unroll
  for (int k = 0; k < 32; k += 8) {
    float v = tl[tx][ty + k];
    u16 h = f2b(v);
    outH[(size_t)(cc0 + k) * R + rr] = h;
    outL[(size_t)(cc0 + k) * R + rr] = f2b(v - b2f(h));
  }
}

__global__ __launch_bounds__(256) void k_ln_embed(const int* __restrict__ idx,
                                                  const float* __restrict__ embed,
                                                  float* __restrict__ x, u16* __restrict__ xbH,
                                                  u16* __restrict__ xbL) {
  int lane = threadIdx.x & 63, wid = threadIdx.x >> 6;
  int r = blockIdx.x * 4 + wid;
  int id = idx[r] & 255;
  float4 v = ((const float4*)(embed + (size_t)id * 256))[lane];
  float m = wsum(v.x + v.y + v.z + v.w) * (1.0f / 256.0f);
  float d0 = v.x - m, d1 = v.y - m, d2 = v.z - m, d3 = v.w - m;
  float var = wsum(d0 * d0 + d1 * d1 + d2 * d2 + d3 * d3) * (1.0f / 256.0f);
  float rs = 1.0f / sqrtf(var + 1e-5f);
  float y0 = d0 * rs, y1 = d1 * rs, y2 = d2 * rs, y3 = d3 * rs;
  ((float4*)(x + (size_t)r * 256))[lane] = make_float4(y0, y1, y2, y3);
  ushort4 oh, ol;
  oh.x = f2b(y0); ol.x = f2b(y0 - b2f(oh.x));
  oh.y = f2b(y1); ol.y = f2b(y1 - b2f(oh.y));
  oh.z = f2b(y2); ol.z = f2b(y2 - b2f(oh.z));
  oh.w = f2b(y3); ol.w = f2b(y3 - b2f(oh.w));
  ((ushort4*)(xbH + (size_t)r * 256))[lane] = oh;
  ((ushort4*)(xbL + (size_t)r * 256))[lane] = ol;
}

__global__ __launch_bounds__(256) void k_xbt(const u16* __restrict__ xbH,
                                             u16* __restrict__ xbTH) {
  int id = blockIdx.x * 256 + threadIdx.x;
  int b = id >> 19;
  int w19 = id & 524287;
  int t = w19 & 2047, d = w19 >> 11;
  xbTH[id] = xbH[(size_t)b * XB_E + (size_t)t * 256 + d];
}

// ---------- GEMM kernels ----------
// 64KB dbuf preamble (g1/g4a/g3/g4b): 2 buffers x 2 tiles
#define GEMM_PRE1D                                                      \
  __shared__ short smd1[32768];                                         \
  float* bounce = (float*)smd1;                                         \
  int tid = threadIdx.x;                                                \
  int lane = tid & 63, wid = tid >> 6;                                  \
  int wr = wid >> 1, wc = wid & 1;                                      \
  f4 acc[4][4];                                                         \
  acc_zero(acc);

// G1: x_sparse=relu(xbH@enc_hi[h]) -> rope -> QR hi.  dbuf. grid(16,32,8): z=bb*4+h.
__global__ __launch_bounds__(256) void k_g1(const u16* __restrict__ xbH,
                                            const u16* __restrict__ etH,
                                            const float2* __restrict__ csA,
                                            const float2* __restrict__ csB,
                                            u16* __restrict__ QRH) {
  GEMM_PRE1D
  int it = blockIdx.x, jt = blockIdx.y;
  int h = blockIdx.z & 3, bb = blockIdx.z >> 2;
  size_t ao = (size_t)bb * XB_E + (size_t)it * 128 * 256;
  size_t bo = (size_t)h * NN_ * 256 + (size_t)jt * 128 * 256;
  {  // prologue
    stage_t(xbH + ao, 256, smd1, wid, lane);
    stage_t(etH + bo, 256, smd1 + 8192, wid, lane);
  }
  for (int kb = 0; kb < 4; ++kb) {
    short* cur = smd1 + (kb & 1) * 16384;
    __syncthreads();
    if (kb + 1 < 4) {
      short* nxt = smd1 + ((kb + 1) & 1) * 16384;
      stage_t(xbH + ao + (kb + 1) * 64, 256, nxt, wid, lane);
      stage_t(etH + bo + (kb + 1) * 64, 256, nxt + 8192, wid, lane);
    }
    mma64x1(cur, cur + 8192, wr, wc, lane, acc);
  }
  __syncthreads();
#pragma unroll
  for (int pass = 0; pass < 2; ++pass) {
    acc_store_half(bounce, acc, pass, wr, wc, lane, true);
    __syncthreads();
    for (int w = 0; w < 16; ++w) {
      int e = w * 256 + tid;
      int rrel = e >> 6, p = e & 63;
      float v0 = bounce[rrel * 128 + 2 * p], v1 = bounce[rrel * 128 + 2 * p + 1];
      int t = it * 128 + pass * 64 + rrel, pp = jt * 64 + p;
      float2 c = trig_ct(csA, csB, t, pp);
      float q0 = v0 * c.x - v1 * c.y;
      float q1 = v1 * c.x + v0 * c.y;
      u32 hi = (u32)f2b(q0) | ((u32)f2b(q1) << 16);
      ((u32*)QRH)[(size_t)bb * QR_U32 + (size_t)(h * T_ + t) * 2048 + pp] = hi;
    }
    __syncthreads();
  }
}

// G2: S = mask(Qh@Qh^T), 1-term, ROW-PAIR blocks (256x384), 512 threads,
// 160KB dbuf (2 x A0|A1|B0|B1|B2). grid 216 = 8 XCDs x 27 (exact chunk).
__global__ __launch_bounds__(512) void k_g2(const u16* __restrict__ QRH,
                                            u16* __restrict__ SpH) {
  __shared__ short smp[81920];             // 160KB
  float* bounce = (float*)smp;             // 32KB [64][128] f32 (epilogue)
  int tid = threadIdx.x;
  int lane = tid & 63, wid = tid >> 6;     // 0..7
  int wr = wid >> 1, wc = wid & 1;         // 4 row-quarters (64) x 2 col-halves (192)
  f4 acc[4][12];
#pragma unroll
  for (int m = 0; m < 4; ++m)
#pragma unroll
    for (int n = 0; n < 12; ++n)
#pragma unroll
      for (int j = 0; j < 4; ++j) acc[m][n][j] = 0.0f;
  int orig = blockIdx.x;
  int lb = (orig & 7) * 27 + (orig >> 3);  // 216 = 8*27 exact
  int bb = lb / 108;
  int l2 = lb % 108;
  int h = l2 / 27;
  int rem = l2 % 27, P = 0;
  while (rem >= (2 * P + 4) / 3) { rem -= (2 * P + 4) / 3; ++P; }
  int j0 = rem * 3;
  int i1 = 2 * P + 1;
  bool has1 = (j0 + 1 <= i1), has2 = (j0 + 2 <= i1);
  size_t base = (size_t)bb * QR_E + (size_t)h * T_ * NN_;
  size_t ao = base + (size_t)P * 256 * NN_;        // A pair: rows [256P, 256P+256)
  size_t bo0 = base + (size_t)j0 * 128 * NN_;
  size_t bo1 = base + (size_t)(j0 + 1) * 128 * NN_;
  size_t bo2 = base + (size_t)(j0 + 2) * 128 * NN_;
  {  // prologue: stage k=0 into buf0
    stage_t8(QRH + ao, NN_, smp, wid, lane);
    stage_t8(QRH + ao + 128 * NN_, NN_, smp + 8192, wid, lane);
    stage_t8(QRH + bo0, NN_, smp + 16384, wid, lane);
    if (has1) stage_t8(QRH + bo1, NN_, smp + 24576, wid, lane);
    if (has2) stage_t8(QRH + bo2, NN_, smp + 32768, wid, lane);
  }
  int r15 = lane & 15, hi4 = lane >> 4;
  int sw = (r15 & 7) << 3;
  for (int kb = 0; kb < 64; ++kb) {
    short* cur = smp + (kb & 1) * 40960;
    __syncthreads();
    if (kb + 1 < 64) {
      short* nxt = smp + ((kb + 1) & 1) * 40960;
      stage_t8(QRH + ao + (kb + 1) * 64, NN_, nxt, wid, lane);
      stage_t8(QRH + ao + 128 * NN_ + (kb + 1) * 64, NN_, nxt + 8192, wid, lane);
      stage_t8(QRH + bo0 + (kb + 1) * 64, NN_, nxt + 16384, wid, lane);
      if (has1) stage_t8(QRH + bo1 + (kb + 1) * 64, NN_, nxt + 24576, wid, lane);
      if (has2) stage_t8(QRH + bo2 + (kb + 1) * 64, NN_, nxt + 32768, wid, lane);
    }
#pragma unroll
    for (int kk = 0; kk < 2; ++kk) {
      int ko = (kk * 32 + hi4 * 8) ^ sw;
      bf8 ah[4];
#pragma unroll
      for (int m = 0; m < 4; ++m) {
        int row = wr * 64 + m * 16 + r15;        // [0,256)
        ah[m] = *(const bf8*)(cur + (row >> 7) * 8192 + (row & 127) * 64 + ko);
      }
#pragma unroll
      for (int n = 0; n < 12; ++n) {
        int cn = wc * 192 + n * 16;              // [0,384)
        int bp = cn >> 7;
        if (bp == 1 && !has1) continue;
        if (bp == 2 && !has2) continue;
        bf8 bh = *(const bf8*)(cur + 16384 + bp * 8192 + ((cn & 127) + r15) * 64 + ko);
#pragma unroll
        for (int m = 0; m < 4; ++m)
          acc[m][n] = __builtin_amdgcn_mfma_f32_16x16x32_bf16(ah[m], bh, acc[m][n], 0, 0, 0);
      }
    }
  }
  __syncthreads();
  // epilogue: 2 row-blocks x up to 3 panels, 2 passes each via 32KB bounce
  int q4 = lane >> 4;
#pragma unroll
  for (int ib = 0; ib < 2; ++ib) {
    int i = 2 * P + ib;
#pragma unroll
    for (int jb = 0; jb < 3; ++jb) {
      int j = j0 + jb;
      if (j > i) continue;                       // not stored (incl. boundary block)
      size_t dblk = (size_t)h * 136 + (size_t)i * (i + 1) / 2 + j;
      bool diag = (i == j);
#pragma unroll
      for (int pass = 0; pass < 2; ++pass) {
        if (wr == 2 * ib + pass) {
#pragma unroll
          for (int m = 0; m < 4; ++m)
#pragma unroll
            for (int n = 0; n < 12; ++n) {
              int cn = wc * 192 + n * 16;
              if ((cn >> 7) != jb) continue;
#pragma unroll
              for (int jj = 0; jj < 4; ++jj)
                bounce[(m * 16 + q4 * 4 + jj) * 128 + (cn & 127) + r15] = acc[m][n][jj];
            }
        }
        __syncthreads();
        for (int w = 0; w < 8; ++w) {
          int e = w * 512 + tid;
          int rrel = e >> 6, p = e & 63;
          int row = pass * 64 + rrel;
          float s0 = bounce[rrel * 128 + 2 * p], s1 = bounce[rrel * 128 + 2 * p + 1];
          if (diag) {  // strictly lower: col < row
            if (2 * p >= row) s0 = 0.0f;
            if (2 * p + 1 >= row) s1 = 0.0f;
          }
          u32 hi = (u32)f2b(s0) | ((u32)f2b(s1) << 16);
          ((u32*)SpH)[(size_t)bb * SP_U32 + dblk * 8192 + row * 64 + p] = hi;
        }
        __syncthreads();
      }
    }
  }
}

// G3: yKV = S_hi @ xbTH, 1-term, full K, 64KB dbuf.  grid(16,2,8): z = bb*4+h.
__global__ __launch_bounds__(256) void k_g3(const u16* __restrict__ SpH,
                                            const u16* __restrict__ xbTH,
                                            float* __restrict__ yKV) {
  GEMM_PRE1D
  int i = blockIdx.x, jt = blockIdx.y;
  int h = blockIdx.z & 3, bb = blockIdx.z >> 2;
  size_t tri = (size_t)bb * 544 + (size_t)h * 136 + (size_t)i * (i + 1) / 2;
  size_t bo = (size_t)bb * XB_E + (size_t)jt * 128 * T_;
  int nk = 2 * (i + 1);
  {  // prologue
    stage_t(SpH + tri * 16384, 128, smd1, wid, lane);
    stage_t(xbTH + bo, T_, smd1 + 8192, wid, lane);
  }
  for (int kb = 0; kb < nk; ++kb) {
    short* cur = smd1 + (kb & 1) * 16384;
    __syncthreads();
    if (kb + 1 < nk) {
      short* nxt = smd1 + ((kb + 1) & 1) * 16384;
      size_t aoff = (tri + ((kb + 1) >> 1)) * 16384 + ((kb + 1) & 1) * 64;
      stage_t(SpH + aoff, 128, nxt, wid, lane);
      stage_t(xbTH + bo + (kb + 1) * 64, T_, nxt + 8192, wid, lane);
    }
    mma64x1(cur, cur + 8192, wr, wc, lane, acc);
  }
  __syncthreads();
#pragma unroll
  for (int pass = 0; pass < 2; ++pass) {
    acc_store_half(bounce, acc, pass, wr, wc, lane, false);
    __syncthreads();
    for (int w = 0; w < 32; ++w) {
      int e = w * 256 + tid;
      int row = e >> 7, col = e & 127;
      yKV[(size_t)bb * YKV_F + ((size_t)h * T_ + i * 128 + pass * 64 + row) * 256 + jt * 128 + col] =
          bounce[row * 128 + col];
    }
    __syncthreads();
  }
}

// LN over f32 rows of 256 -> hi bf16.  4096 blocks.
__global__ __launch_bounds__(256) void k_ln_f32(const float* __restrict__ in,
                                                u16* __restrict__ outH) {
  int lane = threadIdx.x & 63, wid = threadIdx.x >> 6;
  int r = blockIdx.x * 4 + wid;
  float4 v = ((const float4*)(in + (size_t)r * 256))[lane];
  float m = wsum(v.x + v.y + v.z + v.w) * (1.0f / 256.0f);
  float d0 = v.x - m, d1 = v.y - m, d2 = v.z - m, d3 = v.w - m;
  float var = wsum(d0 * d0 + d1 * d1 + d2 * d2 + d3 * d3) * (1.0f / 256.0f);
  float rs = 1.0f / sqrtf(var + 1e-5f);
  ushort4 oh;
  oh.x = f2b(d0 * rs); oh.y = f2b(d1 * rs); oh.z = f2b(d2 * rs); oh.w = f2b(d3 * rs);
  ((ushort4*)(outH + (size_t)r * 256))[lane] = oh;
}

// G4a: y_sparse=relu(ykH@encv_hi[h]); gate by invrope(QR hi); xy -> QR hi.
// dbuf. grid(16,32,8): z = bb*4+h.
__global__ __launch_bounds__(256) void k_g4a(const u16* __restrict__ ykH,
                                             const u16* __restrict__ evH,
                                             const float2* __restrict__ csA,
                                             const float2* __restrict__ csB,
                                             u16* __restrict__ QRH) {
  GEMM_PRE1D
  int it = blockIdx.x, jt = blockIdx.y;
  int h = blockIdx.z & 3, bb = blockIdx.z >> 2;
  int t0 = it * 128;
  size_t ao = (size_t)bb * YKH_E + (size_t)(h * T_ + t0) * 256;
  size_t bo = (size_t)h * NN_ * 256 + (size_t)jt * 128 * 256;
  {  // prologue
    stage_t(ykH + ao, 256, smd1, wid, lane);
    stage_t(evH + bo, 256, smd1 + 8192, wid, lane);
  }
  for (int kb = 0; kb < 4; ++kb) {
    short* cur = smd1 + (kb & 1) * 16384;
    __syncthreads();
    if (kb + 1 < 4) {
      short* nxt = smd1 + ((kb + 1) & 1) * 16384;
      stage_t(ykH + ao + (kb + 1) * 64, 256, nxt, wid, lane);
      stage_t(evH + bo + (kb + 1) * 64, 256, nxt + 8192, wid, lane);
    }
    mma64x1(cur, cur + 8192, wr, wc, lane, acc);
  }
  __syncthreads();
#pragma unroll
  for (int pass = 0; pass < 2; ++pass) {
    acc_store_half(bounce, acc, pass, wr, wc, lane, true);
    __syncthreads();
    for (int w = 0; w < 16; ++w) {
      int e = w * 256 + tid;
      int rrel = e >> 6, p = e & 63;
      float ys0 = bounce[rrel * 128 + 2 * p], ys1 = bounce[rrel * 128 + 2 * p + 1];
      int t = t0 + pass * 64 + rrel, pp = jt * 64 + p;
      size_t u32b = (size_t)bb * QR_U32 + (size_t)(h * T_ + t) * 2048 + pp;
      u32 qh = ((const u32*)QRH)[u32b];
      float qe = b2f((u16)(qh & 0xffff));
      float qo = b2f((u16)(qh >> 16));
      float2 c = trig_ct(csA, csB, t, pp);
      float xe = fmaxf(qe * c.x + qo * c.y, 0.0f);
      float xo = fmaxf(qo * c.x - qe * c.y, 0.0f);
      u32 hi = (u32)f2b(ys0 * xe) | ((u32)f2b(ys1 * xo) << 16);
      ((u32*)QRH)[u32b] = hi;
    }
    __syncthreads();
  }
}

// G4b: part[bb][h+4*ks] = xyH[ks-half] @ dec_hi[h][ks-half].  1-term, 64KB dbuf.
// grid(16,2,16): h = z&3, ks = (z>>2)&1, bb = z>>3.
__global__ __launch_bounds__(256) void k_g4b(const u16* __restrict__ xyH,
                                             const u16* __restrict__ dtH,
                                             float* __restrict__ part) {
  GEMM_PRE1D
  int it = blockIdx.x, jt = blockIdx.y;
  int h = blockIdx.z & 3, ks = (blockIdx.z >> 2) & 1, bb = blockIdx.z >> 3;
  int z8 = h + 4 * ks;
  int t0 = it * 128;
  size_t ao = (size_t)bb * QR_E + (size_t)(h * T_ + t0) * NN_;
  size_t bo = (size_t)h * D_ * NN_ + (size_t)jt * 128 * NN_;
  int k0 = ks * 32, k1 = ks * 32 + 32;
  {  // prologue
    stage_t(xyH + ao + k0 * 64, NN_, smd1, wid, lane);
    stage_t(dtH + bo + k0 * 64, NN_, smd1 + 8192, wid, lane);
  }
  for (int kb = k0; kb < k1; ++kb) {
    short* cur = smd1 + ((kb - k0) & 1) * 16384;
    __syncthreads();
    if (kb + 1 < k1) {
      short* nxt = smd1 + ((kb + 1 - k0) & 1) * 16384;
      stage_t(xyH + ao + (kb + 1) * 64, NN_, nxt, wid, lane);
      stage_t(dtH + bo + (kb + 1) * 64, NN_, nxt + 8192, wid, lane);
    }
    mma64x1(cur, cur + 8192, wr, wc, lane, acc);
  }
  __syncthreads();
#pragma unroll
  for (int pass = 0; pass < 2; ++pass) {
    acc_store_half(bounce, acc, pass, wr, wc, lane, false);
    __syncthreads();
    for (int w = 0; w < 32; ++w) {
      int e = w * 256 + tid;
      int row = e >> 7, col = e & 127;
      part[(size_t)bb * SP_F + ((size_t)z8 * T_ + t0 + pass * 64 + row) * 256 + jt * 128 + col] =
          bounce[row * 128 + col];
    }
    __syncthreads();
  }
}

// LN3: yMLP = sum of 8 part slabs; x = ln(x + ln(yMLP)); refresh x, xb hi/lo.
// 1024 blocks, r in [0,4096): bb = r>>11.
__global__ __launch_bounds__(256) void k_ln3(const float* __restrict__ part, float* __restrict__ x,
                                             u16* __restrict__ xbH, u16* __restrict__ xbL) {
  int lane = threadIdx.x & 63, wid = threadIdx.x >> 6;
  int r = blockIdx.x * 4 + wid;
  int bb = r >> 11, rl = r & 2047;
  const float* P = part + (size_t)bb * SP_F;
  float a0 = 0, a1 = 0, a2 = 0, a3 = 0;
#pragma unroll
  for (int h = 0; h < 8; ++h) {
    float4 u = ((const float4*)(P + ((size_t)h * T_ + rl) * 256))[lane];
    a0 += u.x; a1 += u.y; a2 += u.z; a3 += u.w;
  }
  float m = wsum(a0 + a1 + a2 + a3) * (1.0f / 256.0f);
  float d0 = a0 - m, d1 = a1 - m, d2 = a2 - m, d3 = a3 - m;
  float var = wsum(d0 * d0 + d1 * d1 + d2 * d2 + d3 * d3) * (1.0f / 256.0f);
  float rs = 1.0f / sqrtf(var + 1e-5f);
  float4 xv = ((const float4*)(x + (size_t)r * 256))[lane];
  float s0 = xv.x + d0 * rs, s1 = xv.y + d1 * rs, s2 = xv.z + d2 * rs, s3 = xv.w + d3 * rs;
  float m2 = wsum(s0 + s1 + s2 + s3) * (1.0f / 256.0f);
  float e0 = s0 - m2, e1 = s1 - m2, e2 = s2 - m2, e3 = s3 - m2;
  float var2 = wsum(e0 * e0 + e1 * e1 + e2 * e2 + e3 * e3) * (1.0f / 256.0f);
  float rs2 = 1.0f / sqrtf(var2 + 1e-5f);
  float y0 = e0 * rs2, y1 = e1 * rs2, y2 = e2 * rs2, y3 = e3 * rs2;
  ((float4*)(x + (size_t)r * 256))[lane] = make_float4(y0, y1, y2, y3);
  ushort4 oh, ol;
  oh.x = f2b(y0); ol.x = f2b(y0 - b2f(oh.x));
  oh.y = f2b(y1); ol.y = f2b(y1 - b2f(oh.y));
  oh.z = f2b(y2); ol.z = f2b(y2 - b2f(oh.z));
  oh.w = f2b(y3); ol.w = f2b(y3 - b2f(oh.w));
  ((ushort4*)(xbH + (size_t)r * 256))[lane] = oh;
  ((ushort4*)(xbL + (size_t)r * 256))[lane] = ol;
}

// G5: logits = xb @ lm_head (3-term) -> f32 out.  grid(32,2).
__global__ __launch_bounds__(256) void k_g5(const u16* __restrict__ xbH,
                                            const u16* __restrict__ xbL,
                                            const u16* __restrict__ lmH,
                                            const u16* __restrict__ lmL,
                                            float* __restrict__ out) {
  __shared__ float smf[16384];
  short* AsH = (short*)smf;
  short* AsL = AsH + 8192;
  short* BsH = AsH + 16384;
  short* BsL = AsH + 24576;
  int tid = threadIdx.x;
  int lane = tid & 63, wid = tid >> 6;
  int wr = wid >> 1, wc = wid & 1;
  f4 acc[4][4];
  acc_zero(acc);
  int it = blockIdx.x, jt = blockIdx.y;
  size_t ao = (size_t)it * 128 * 256;
  size_t bo = (size_t)jt * 128 * 256;
  for (int kb = 0; kb < 4; ++kb) {
    stage_t(xbH + ao + kb * 64, 256, AsH, wid, lane);
    stage_t(xbL + ao + kb * 64, 256, AsL, wid, lane);
    stage_t(lmH + bo + kb * 64, 256, BsH, wid, lane);
    stage_t(lmL + bo + kb * 64, 256, BsL, wid, lane);
    __syncthreads();
    mma64x3(AsH, AsL, BsH, BsL, wr, wc, lane, acc);
    __syncthreads();
  }
  acc_store_f32(smf, acc, wr, wc, lane, false);
  __syncthreads();
  for (int w = 0; w < 64; ++w) {
    int e = w * 256 + tid;
    int row = e >> 7, col = e & 127;
    out[(size_t)(it * 128 + row) * 256 + jt * 128 + col] = smf[row * 128 + col];
  }
}

extern "C" void kernel_launch(void* const* d_in, const int* in_sizes, int n_in, void* d_out,
                              int out_size, void* d_ws, size_t ws_size, hipStream_t stream) {
  const int*   idx   = (const int*)d_in[0];
  const float* embed = (const float*)d_in[1];
  const float* enc   = (const float*)d_in[2];
  const float* encv  = (const float*)d_in[3];
  const float* dec   = (const float*)d_in[4];
  const float* lm    = (const float*)d_in[5];

  if (ws_size < WS_NEED) {
    hipMemsetAsync(d_out, 0x46, (size_t)out_size * 4, stream);
    return;
  }

  char* w = (char*)d_ws;
  float2* csA  = (float2*)(w + CSA_OFF);
  float2* csB  = (float2*)(w + CSB_OFF);
  u16*    etH  = (u16*)(w + ETH_OFF);
  u16*    evH  = (u16*)(w + EVH_OFF);
  u16*    dtH  = (u16*)(w + DTH_OFF);
  u16*    lmH  = (u16*)(w + LMH_OFF);
  u16*    lmL  = (u16*)(w + LML_OFF);
  float*  x    = (float*)(w + X_OFF);
  u16*    xbH  = (u16*)(w + XBH_OFF);
  u16*    xbL  = (u16*)(w + XBL_OFF);
  u16*    xbTH = (u16*)(w + XBTH_OFF);
  u16*    QRH  = (u16*)(w + QRH_OFF);
  u16*    SpH  = (u16*)(w + SH_OFF);
  float*  part = (float*)(w + SH_OFF);
  float*  yKV  = (float*)(w + YKV_OFF);
  u16*    ykH  = (u16*)(w + YKH_OFF);

  k_costab<<<1152, 256, 0, stream>>>(csA, csB);
  k_tcast1<<<dim3(128, 8, 4), dim3(32, 8), 0, stream>>>(enc, etH, 256, 4096);
  k_tcast1<<<dim3(128, 8, 4), dim3(32, 8), 0, stream>>>(encv, evH, 256, 4096);
  k_tcast1<<<dim3(8, 128, 4), dim3(32, 8), 0, stream>>>(dec, dtH, 4096, 256);
  k_tcast2<<<dim3(8, 8, 1), dim3(32, 8), 0, stream>>>(lm, lmH, lmL, 256, 256);
  k_ln_embed<<<1024, 256, 0, stream>>>(idx, embed, x, xbH, xbL);
  k_xbt<<<4096, 256, 0, stream>>>(xbH, xbTH);

  for (int l = 0; l < NLAYER; ++l) {
    k_g1<<<dim3(16, 32, 8), 256, 0, stream>>>(xbH, etH, csA, csB, QRH);
    k_g2<<<216, 512, 0, stream>>>(QRH, SpH);
    k_g3<<<dim3(16, 2, 8), 256, 0, stream>>>(SpH, xbTH, yKV);
    k_ln_f32<<<4096, 256, 0, stream>>>(yKV, ykH);
    k_g4a<<<dim3(16, 32, 8), 256, 0, stream>>>(ykH, evH, csA, csB, QRH);
    k_g4b<<<dim3(16, 2, 16), 256, 0, stream>>>(QRH, dtH, part);
    k_ln3<<<1024, 256, 0, stream>>>(part, x, xbH, xbL);
    k_xbt<<<4096, 256, 0, stream>>>(xbH, xbTH);
  }
  k_g5<<<dim3(32, 2), 256, 0, stream>>>(xbH, xbL, lmH, lmL, (float*)d_out);
}

// Round 23
// 3095.661 us; speedup vs baseline: 1.3084x; 1.3084x over previous
//
#include <hip/hip_runtime.h>

// ===== BDH forward on MI355X — R23: R21 revert + g1/g4a dbuf only =====
// R22 regressed: g2 256x384 acc[4][12]=192 VGPR spilled (VGPR=128, WRITE 77MB
// scratch). R23 = R21's proven g2 (128x384 row-triple, acc[4][6], 88 VGPR,
// 213us) + keep g1/g4a 64KB dbuf (proven g4b pattern). Bit-identical math.

typedef unsigned short u16;
typedef unsigned int   u32;
typedef __attribute__((ext_vector_type(8))) short bf8;
typedef __attribute__((ext_vector_type(4))) float f4;

#define T_  2048
#define D_  256
#define NH_ 4
#define NN_ 4096
#define NLAYER 6

// per-batch strides (elements)
#define XB_E   524288u
#define QR_E   33554432u
#define QR_U32 16777216u
#define SP_U32 4456448u
#define SP_F   4456448u
#define YKV_F  2097152u
#define YKH_E  2097152u

// ---- workspace layout (bytes) ----
#define CSA_OFF  ((size_t)0)
#define CSB_OFF  (CSA_OFF  + 262144)
#define ETH_OFF  (CSB_OFF  + 2097152)
#define EVH_OFF  (ETH_OFF  + 8388608)
#define DTH_OFF  (EVH_OFF  + 8388608)
#define LMH_OFF  (DTH_OFF  + 8388608)
#define LML_OFF  (LMH_OFF  + 131072)
#define X_OFF    (LML_OFF  + 131072)
#define XBH_OFF  (X_OFF    + 4194304)
#define XBL_OFF  (XBH_OFF  + 2097152)
#define XBTH_OFF (XBL_OFF  + 2097152)
#define QRH_OFF  (XBTH_OFF + 2097152)
#define SH_OFF   (QRH_OFF  + 134217728)
#define YKV_OFF  (SH_OFF   + 35651584)
#define YKH_OFF  (YKV_OFF  + 16777216)
#define WS_NEED  (YKH_OFF  + 8388608)

// ---------- helpers ----------
__device__ __forceinline__ u16 f2b(float f) {
  u32 u = __builtin_bit_cast(u32, f);
  u32 r = u + 0x7fffu + ((u >> 16) & 1u);
  return (u16)(r >> 16);
}
__device__ __forceinline__ float b2f(u16 h) {
  u32 u = ((u32)h) << 16;
  return __builtin_bit_cast(float, u);
}
__device__ __forceinline__ float wsum(float v) {
#pragma unroll
  for (int o = 32; o; o >>= 1) v += __shfl_xor(v, o, 64);
  return v;
}
__device__ __forceinline__ float2 trig_ct(const float2* csA, const float2* csB, int t, int pp) {
  float2 a = csA[(t >> 7) * 2048 + pp];
  float2 b = csB[(t & 127) * 2048 + pp];
  return make_float2(a.x * b.x - a.y * b.y, a.x * b.y + a.y * b.x);
}
__device__ __forceinline__ void gld16(const u16* g, short* l) {
  __builtin_amdgcn_global_load_lds(
      (const __attribute__((address_space(1))) u32*)g,
      (__attribute__((address_space(3))) u32*)l, 16, 0, 0);
}
__device__ __forceinline__ void stage_t(const u16* g, int lda, short* s, int wid, int lane) {
  int r8 = lane >> 3;
  int c8 = ((lane & 7) ^ r8) * 8;
#pragma unroll
  for (int j = 0; j < 4; ++j) {
    int row = wid * 32 + j * 8;
    gld16(g + (size_t)(row + r8) * lda + c8, s + row * 64);
  }
}
__device__ __forceinline__ void stage_t8(const u16* g, int lda, short* s, int wid, int lane) {
  int r8 = lane >> 3;
  int c8 = ((lane & 7) ^ r8) * 8;
#pragma unroll
  for (int j = 0; j < 2; ++j) {
    int row = wid * 16 + j * 8;
    gld16(g + (size_t)(row + r8) * lda + c8, s + row * 64);
  }
}
// 3-term split: 96 MFMA — g5 only
__device__ __forceinline__ void mma64x3(const short* AsH, const short* AsL, const short* BsH,
                                        const short* BsL, int wr, int wc, int lane,
                                        f4 acc[4][4]) {
  int r15 = lane & 15, hi = lane >> 4;
  int sw = (r15 & 7) << 3;
#pragma unroll
  for (int kk = 0; kk < 2; ++kk) {
    int ko = (kk * 32 + hi * 8) ^ sw;
    bf8 ah[4], al[4], bh[4], bl[4];
#pragma unroll
    for (int m = 0; m < 4; ++m) {
      int off = (wr * 64 + m * 16 + r15) * 64 + ko;
      ah[m] = *(const bf8*)(AsH + off);
      al[m] = *(const bf8*)(AsL + off);
    }
#pragma unroll
    for (int n = 0; n < 4; ++n) {
      int off = (wc * 64 + n * 16 + r15) * 64 + ko;
      bh[n] = *(const bf8*)(BsH + off);
      bl[n] = *(const bf8*)(BsL + off);
    }
#pragma unroll
    for (int m = 0; m < 4; ++m)
#pragma unroll
      for (int n = 0; n < 4; ++n) {
        acc[m][n] = __builtin_amdgcn_mfma_f32_16x16x32_bf16(ah[m], bh[n], acc[m][n], 0, 0, 0);
        acc[m][n] = __builtin_amdgcn_mfma_f32_16x16x32_bf16(al[m], bh[n], acc[m][n], 0, 0, 0);
        acc[m][n] = __builtin_amdgcn_mfma_f32_16x16x32_bf16(ah[m], bl[n], acc[m][n], 0, 0, 0);
      }
  }
}
// 1-term: 32 MFMA — g1/g3/g4a/g4b
__device__ __forceinline__ void mma64x1(const short* AsH, const short* BsH,
                                        int wr, int wc, int lane, f4 acc[4][4]) {
  int r15 = lane & 15, hi = lane >> 4;
  int sw = (r15 & 7) << 3;
#pragma unroll
  for (int kk = 0; kk < 2; ++kk) {
    int ko = (kk * 32 + hi * 8) ^ sw;
    bf8 ah[4], bh[4];
#pragma unroll
    for (int m = 0; m < 4; ++m)
      ah[m] = *(const bf8*)(AsH + (wr * 64 + m * 16 + r15) * 64 + ko);
#pragma unroll
    for (int n = 0; n < 4; ++n)
      bh[n] = *(const bf8*)(BsH + (wc * 64 + n * 16 + r15) * 64 + ko);
#pragma unroll
    for (int m = 0; m < 4; ++m)
#pragma unroll
      for (int n = 0; n < 4; ++n)
        acc[m][n] = __builtin_amdgcn_mfma_f32_16x16x32_bf16(ah[m], bh[n], acc[m][n], 0, 0, 0);
  }
}
__device__ __forceinline__ void acc_zero(f4 acc[4][4]) {
#pragma unroll
  for (int m = 0; m < 4; ++m)
#pragma unroll
    for (int n = 0; n < 4; ++n)
#pragma unroll
      for (int j = 0; j < 4; ++j) acc[m][n][j] = 0.0f;
}
__device__ __forceinline__ void acc_store_f32(float* F, f4 acc[4][4], int wr, int wc, int lane,
                                              bool relu) {
  int r15 = lane & 15, q = lane >> 4;
#pragma unroll
  for (int m = 0; m < 4; ++m)
#pragma unroll
    for (int n = 0; n < 4; ++n)
#pragma unroll
      for (int j = 0; j < 4; ++j) {
        float v = acc[m][n][j];
        if (relu) v = fmaxf(v, 0.0f);
        F[(wr * 64 + m * 16 + q * 4 + j) * 128 + wc * 64 + n * 16 + r15] = v;
      }
}
__device__ __forceinline__ void acc_store_half(float* F, f4 acc[4][4], int pass, int wr, int wc,
                                               int lane, bool relu) {
  if (wr != pass) return;
  int r15 = lane & 15, q = lane >> 4;
#pragma unroll
  for (int m = 0; m < 4; ++m)
#pragma unroll
    for (int n = 0; n < 4; ++n)
#pragma unroll
      for (int j = 0; j < 4; ++j) {
        float v = acc[m][n][j];
        if (relu) v = fmaxf(v, 0.0f);
        F[(m * 16 + q * 4 + j) * 128 + wc * 64 + n * 16 + r15] = v;
      }
}

// ---------- prep kernels ----------
__global__ __launch_bounds__(256) void k_costab(float2* csA, float2* csB) {
  int id = blockIdx.x * 256 + threadIdx.x;
  int r = id >> 11, p = id & 2047;
  double freq = exp2(-(double)p / 128.0) * 0.15915494309189533577;
  int t = (r < 16) ? (r * 128) : (r - 16);
  double ph = fmod((double)t * freq, 1.0);
  double ang = ph * 6.2831853071795864769;
  float2 v = make_float2((float)cos(ang), (float)sin(ang));
  if (r < 16) csA[r * 2048 + p] = v;
  else        csB[(r - 16) * 2048 + p] = v;
}

__global__ __launch_bounds__(256) void k_tcast1(const float* __restrict__ in,
                                                u16* __restrict__ outH, int R, int C) {
  __shared__ float tl[32][33];
  size_t bo = (size_t)blockIdx.z * R * C;
  int tx = threadIdx.x, ty = threadIdx.y;
  int c = blockIdx.x * 32 + tx, r0 = blockIdx.y * 32 + ty;
#pragma unroll
  for (int k = 0; k < 32; k += 8) tl[ty + k][tx] = in[bo + (size_t)(r0 + k) * C + c];
  __syncthreads();
  int rr = blockIdx.y * 32 + tx, cc0 = blockIdx.x * 32 + ty;
#pragma unroll
  for (int k = 0; k < 32; k += 8) outH[bo + (size_t)(cc0 + k) * R + rr] = f2b(tl[tx][ty + k]);
}

__global__ __launch_bounds__(256) void k_tcast2(const float* __restrict__ in,
                                                u16* __restrict__ outH, u16* __restrict__ outL,
                                                int R, int C) {
  __shared__ float tl[32][33];
  int tx = threadIdx.x, ty = threadIdx.y;
  int c = blockIdx.x * 32 + tx, r0 = blockIdx.y * 32 + ty;
#pragma unroll
  for (int k = 0; k < 32; k += 8) tl[ty + k][tx] = in[(size_t)(r0 + k) * C + c];
  __syncthreads();
  int rr = blockIdx.y * 32 + tx, cc0 = blockIdx.x * 32 + ty;
#pragma unroll
  for (int k = 0; k < 32; k += 8) {
    float v = tl[tx][ty + k];
    u16 h = f2b(v);
    outH[(size_t)(cc0 + k) * R + rr] = h;
    outL[(size_t)(cc0 + k) * R + rr] = f2b(v - b2f(h));
  }
}

__global__ __launch_bounds__(256) void k_ln_embed(const int* __restrict__ idx,
                                                  const float* __restrict__ embed,
                                                  float* __restrict__ x, u16* __restrict__ xbH,
                                                  u16* __restrict__ xbL) {
  int lane = threadIdx.x & 63, wid = threadIdx.x >> 6;
  int r = blockIdx.x * 4 + wid;
  int id = idx[r] & 255;
  float4 v = ((const float4*)(embed + (size_t)id * 256))[lane];
  float m = wsum(v.x + v.y + v.z + v.w) * (1.0f / 256.0f);
  float d0 = v.x - m, d1 = v.y - m, d2 = v.z - m, d3 = v.w - m;
  float var = wsum(d0 * d0 + d1 * d1 + d2 * d2 + d3 * d3) * (1.0f / 256.0f);
  float rs = 1.0f / sqrtf(var + 1e-5f);
  float y0 = d0 * rs, y1 = d1 * rs, y2 = d2 * rs, y3 = d3 * rs;
  ((float4*)(x + (size_t)r * 256))[lane] = make_float4(y0, y1, y2, y3);
  ushort4 oh, ol;
  oh.x = f2b(y0); ol.x = f2b(y0 - b2f(oh.x));
  oh.y = f2b(y1); ol.y = f2b(y1 - b2f(oh.y));
  oh.z = f2b(y2); ol.z = f2b(y2 - b2f(oh.z));
  oh.w = f2b(y3); ol.w = f2b(y3 - b2f(oh.w));
  ((ushort4*)(xbH + (size_t)r * 256))[lane] = oh;
  ((ushort4*)(xbL + (size_t)r * 256))[lane] = ol;
}

__global__ __launch_bounds__(256) void k_xbt(const u16* __restrict__ xbH,
                                             u16* __restrict__ xbTH) {
  int id = blockIdx.x * 256 + threadIdx.x;
  int b = id >> 19;
  int w19 = id & 524287;
  int t = w19 & 2047, d = w19 >> 11;
  xbTH[id] = xbH[(size_t)b * XB_E + (size_t)t * 256 + d];
}

// ---------- GEMM kernels ----------
#define GEMM_PRE1D                                                      \
  __shared__ short smd1[32768];                                         \
  float* bounce = (float*)smd1;                                         \
  int tid = threadIdx.x;                                                \
  int lane = tid & 63, wid = tid >> 6;                                  \
  int wr = wid >> 1, wc = wid & 1;                                      \
  f4 acc[4][4];                                                         \
  acc_zero(acc);

// G1: x_sparse=relu(xbH@enc_hi[h]) -> rope -> QR hi.  dbuf. grid(16,32,8): z=bb*4+h.
__global__ __launch_bounds__(256) void k_g1(const u16* __restrict__ xbH,
                                            const u16* __restrict__ etH,
                                            const float2* __restrict__ csA,
                                            const float2* __restrict__ csB,
                                            u16* __restrict__ QRH) {
  GEMM_PRE1D
  int it = blockIdx.x, jt = blockIdx.y;
  int h = blockIdx.z & 3, bb = blockIdx.z >> 2;
  size_t ao = (size_t)bb * XB_E + (size_t)it * 128 * 256;
  size_t bo = (size_t)h * NN_ * 256 + (size_t)jt * 128 * 256;
  {  // prologue
    stage_t(xbH + ao, 256, smd1, wid, lane);
    stage_t(etH + bo, 256, smd1 + 8192, wid, lane);
  }
  for (int kb = 0; kb < 4; ++kb) {
    short* cur = smd1 + (kb & 1) * 16384;
    __syncthreads();
    if (kb + 1 < 4) {
      short* nxt = smd1 + ((kb + 1) & 1) * 16384;
      stage_t(xbH + ao + (kb + 1) * 64, 256, nxt, wid, lane);
      stage_t(etH + bo + (kb + 1) * 64, 256, nxt + 8192, wid, lane);
    }
    mma64x1(cur, cur + 8192, wr, wc, lane, acc);
  }
  __syncthreads();
#pragma unroll
  for (int pass = 0; pass < 2; ++pass) {
    acc_store_half(bounce, acc, pass, wr, wc, lane, true);
    __syncthreads();
    for (int w = 0; w < 16; ++w) {
      int e = w * 256 + tid;
      int rrel = e >> 6, p = e & 63;
      float v0 = bounce[rrel * 128 + 2 * p], v1 = bounce[rrel * 128 + 2 * p + 1];
      int t = it * 128 + pass * 64 + rrel, pp = jt * 64 + p;
      float2 c = trig_ct(csA, csB, t, pp);
      float q0 = v0 * c.x - v1 * c.y;
      float q1 = v1 * c.x + v0 * c.y;
      u32 hi = (u32)f2b(q0) | ((u32)f2b(q1) << 16);
      ((u32*)QRH)[(size_t)bb * QR_U32 + (size_t)(h * T_ + t) * 2048 + pp] = hi;
    }
    __syncthreads();
  }
}

// G2: S = mask(Qh@Qh^T), 1-term, row-triple 128x384, 512 threads, 128KB dbuf.
// grid 408 = 8 XCDs x 51 (exact chunk).  (R21 proven version)
__global__ __launch_bounds__(512) void k_g2(const u16* __restrict__ QRH,
                                            u16* __restrict__ SpH) {
  __shared__ short smp[65536];             // 128KB: 2 x (AsH|B0|B1|B2)
  float* bounce = (float*)smp;
  int tid = threadIdx.x;
  int lane = tid & 63, wid = tid >> 6;
  int wr = wid >> 2, wc = wid & 3;         // 2 row-halves x 4 col-waves (64x96)
  f4 acc[4][6];
#pragma unroll
  for (int m = 0; m < 4; ++m)
#pragma unroll
    for (int n = 0; n < 6; ++n)
#pragma unroll
      for (int j = 0; j < 4; ++j) acc[m][n][j] = 0.0f;
  int orig = blockIdx.x;
  int lb = (orig & 7) * 51 + (orig >> 3);  // 408 = 8*51 exact chunk
  int bb = lb / 204;
  int l2 = lb % 204;
  int h = l2 / 51;
  int rem = l2 % 51, i = 0;
  while (rem >= (i + 3) / 3) { rem -= (i + 3) / 3; ++i; }
  int j0 = rem * 3, j1 = j0 + 1, j2 = j0 + 2;
  bool has1 = (j1 <= i), has2 = (j2 <= i);
  size_t base = (size_t)bb * QR_E + (size_t)h * T_ * NN_;
  size_t ao = base + (size_t)i * 128 * NN_;
  size_t bo0 = base + (size_t)j0 * 128 * NN_;
  size_t bo1 = base + (size_t)j1 * 128 * NN_;
  size_t bo2 = base + (size_t)j2 * 128 * NN_;
  {  // prologue: stage k=0 into buf0
    stage_t8(QRH + ao, NN_, smp, wid, lane);
    stage_t8(QRH + bo0, NN_, smp + 8192, wid, lane);
    if (has1) stage_t8(QRH + bo1, NN_, smp + 16384, wid, lane);
    if (has2) stage_t8(QRH + bo2, NN_, smp + 24576, wid, lane);
  }
  int r15 = lane & 15, hi4 = lane >> 4;
  int sw = (r15 & 7) << 3;
  for (int kb = 0; kb < 64; ++kb) {
    short* cur = smp + (kb & 1) * 32768;
    __syncthreads();
    if (kb + 1 < 64) {
      short* nxt = smp + ((kb + 1) & 1) * 32768;
      stage_t8(QRH + ao + (kb + 1) * 64, NN_, nxt, wid, lane);
      stage_t8(QRH + bo0 + (kb + 1) * 64, NN_, nxt + 8192, wid, lane);
      if (has1) stage_t8(QRH + bo1 + (kb + 1) * 64, NN_, nxt + 16384, wid, lane);
      if (has2) stage_t8(QRH + bo2 + (kb + 1) * 64, NN_, nxt + 24576, wid, lane);
    }
#pragma unroll
    for (int kk = 0; kk < 2; ++kk) {
      int ko = (kk * 32 + hi4 * 8) ^ sw;
      bf8 ah[4];
#pragma unroll
      for (int m = 0; m < 4; ++m)
        ah[m] = *(const bf8*)(cur + (wr * 64 + m * 16 + r15) * 64 + ko);
#pragma unroll
      for (int n = 0; n < 6; ++n) {
        int cn = wc * 96 + n * 16;
        int bp = cn >> 7;
        if (bp == 1 && !has1) continue;
        if (bp == 2 && !has2) continue;
        bf8 bh = *(const bf8*)(cur + 8192 + bp * 8192 + ((cn & 127) + r15) * 64 + ko);
#pragma unroll
        for (int m = 0; m < 4; ++m)
          acc[m][n] = __builtin_amdgcn_mfma_f32_16x16x32_bf16(ah[m], bh, acc[m][n], 0, 0, 0);
      }
    }
  }
  __syncthreads();
  int q4 = lane >> 4;
#pragma unroll
  for (int jb = 0; jb < 3; ++jb) {
    if (jb == 1 && !has1) break;
    if (jb == 2 && !has2) break;
    int j = j0 + jb;
    size_t dblk = ((size_t)h * 136 + (size_t)i * (i + 1) / 2 + j) * 16384;
    bool diag = (i == j);
#pragma unroll
    for (int pass = 0; pass < 2; ++pass) {
      if (wr == pass) {
#pragma unroll
        for (int m = 0; m < 4; ++m)
#pragma unroll
          for (int n = 0; n < 6; ++n) {
            int cn = wc * 96 + n * 16;
            if ((cn >> 7) != jb) continue;
#pragma unroll
            for (int jj = 0; jj < 4; ++jj)
              bounce[(m * 16 + q4 * 4 + jj) * 128 + (cn & 127) + r15] = acc[m][n][jj];
          }
      }
      __syncthreads();
      for (int w = 0; w < 8; ++w) {
        int e = w * 512 + tid;
        int rrel = e >> 6, p = e & 63;
        int row = pass * 64 + rrel;
        float s0 = bounce[rrel * 128 + 2 * p], s1 = bounce[rrel * 128 + 2 * p + 1];
        if (diag) {  // strictly lower: col < row
          if (2 * p >= row) s0 = 0.0f;
          if (2 * p + 1 >= row) s1 = 0.0f;
        }
        u32 hi = (u32)f2b(s0) | ((u32)f2b(s1) << 16);
        ((u32*)SpH)[(size_t)bb * SP_U32 + (dblk >> 1) + row * 64 + p] = hi;
      }
      __syncthreads();
    }
  }
}

// G3: yKV = S_hi @ xbTH, 1-term, full K, 64KB dbuf.  grid(16,2,8): z = bb*4+h.
__global__ __launch_bounds__(256) void k_g3(const u16* __restrict__ SpH,
                                            const u16* __restrict__ xbTH,
                                            float* __restrict__ yKV) {
  GEMM_PRE1D
  int i = blockIdx.x, jt = blockIdx.y;
  int h = blockIdx.z & 3, bb = blockIdx.z >> 2;
  size_t tri = (size_t)bb * 544 + (size_t)h * 136 + (size_t)i * (i + 1) / 2;
  size_t bo = (size_t)bb * XB_E + (size_t)jt * 128 * T_;
  int nk = 2 * (i + 1);
  {  // prologue
    stage_t(SpH + tri * 16384, 128, smd1, wid, lane);
    stage_t(xbTH + bo, T_, smd1 + 8192, wid, lane);
  }
  for (int kb = 0; kb < nk; ++kb) {
    short* cur = smd1 + (kb & 1) * 16384;
    __syncthreads();
    if (kb + 1 < nk) {
      short* nxt = smd1 + ((kb + 1) & 1) * 16384;
      size_t aoff = (tri + ((kb + 1) >> 1)) * 16384 + ((kb + 1) & 1) * 64;
      stage_t(SpH + aoff, 128, nxt, wid, lane);
      stage_t(xbTH + bo + (kb + 1) * 64, T_, nxt + 8192, wid, lane);
    }
    mma64x1(cur, cur + 8192, wr, wc, lane, acc);
  }
  __syncthreads();
#pragma unroll
  for (int pass = 0; pass < 2; ++pass) {
    acc_store_half(bounce, acc, pass, wr, wc, lane, false);
    __syncthreads();
    for (int w = 0; w < 32; ++w) {
      int e = w * 256 + tid;
      int row = e >> 7, col = e & 127;
      yKV[(size_t)bb * YKV_F + ((size_t)h * T_ + i * 128 + pass * 64 + row) * 256 + jt * 128 + col] =
          bounce[row * 128 + col];
    }
    __syncthreads();
  }
}

// LN over f32 rows of 256 -> hi bf16.  4096 blocks.
__global__ __launch_bounds__(256) void k_ln_f32(const float* __restrict__ in,
                                                u16* __restrict__ outH) {
  int lane = threadIdx.x & 63, wid = threadIdx.x >> 6;
  int r = blockIdx.x * 4 + wid;
  float4 v = ((const float4*)(in + (size_t)r * 256))[lane];
  float m = wsum(v.x + v.y + v.z + v.w) * (1.0f / 256.0f);
  float d0 = v.x - m, d1 = v.y - m, d2 = v.z - m, d3 = v.w - m;
  float var = wsum(d0 * d0 + d1 * d1 + d2 * d2 + d3 * d3) * (1.0f / 256.0f);
  float rs = 1.0f / sqrtf(var + 1e-5f);
  ushort4 oh;
  oh.x = f2b(d0 * rs); oh.y = f2b(d1 * rs); oh.z = f2b(d2 * rs); oh.w = f2b(d3 * rs);
  ((ushort4*)(outH + (size_t)r * 256))[lane] = oh;
}

// G4a: y_sparse=relu(ykH@encv_hi[h]); gate by invrope(QR hi); xy -> QR hi.
// dbuf. grid(16,32,8): z = bb*4+h.
__global__ __launch_bounds__(256) void k_g4a(const u16* __restrict__ ykH,
                                             const u16* __restrict__ evH,
                                             const float2* __restrict__ csA,
                                             const float2* __restrict__ csB,
                                             u16* __restrict__ QRH) {
  GEMM_PRE1D
  int it = blockIdx.x, jt = blockIdx.y;
  int h = blockIdx.z & 3, bb = blockIdx.z >> 2;
  int t0 = it * 128;
  size_t ao = (size_t)bb * YKH_E + (size_t)(h * T_ + t0) * 256;
  size_t bo = (size_t)h * NN_ * 256 + (size_t)jt * 128 * 256;
  {  // prologue
    stage_t(ykH + ao, 256, smd1, wid, lane);
    stage_t(evH + bo, 256, smd1 + 8192, wid, lane);
  }
  for (int kb = 0; kb < 4; ++kb) {
    short* cur = smd1 + (kb & 1) * 16384;
    __syncthreads();
    if (kb + 1 < 4) {
      short* nxt = smd1 + ((kb + 1) & 1) * 16384;
      stage_t(ykH + ao + (kb + 1) * 64, 256, nxt, wid, lane);
      stage_t(evH + bo + (kb + 1) * 64, 256, nxt + 8192, wid, lane);
    }
    mma64x1(cur, cur + 8192, wr, wc, lane, acc);
  }
  __syncthreads();
#pragma unroll
  for (int pass = 0; pass < 2; ++pass) {
    acc_store_half(bounce, acc, pass, wr, wc, lane, true);
    __syncthreads();
    for (int w = 0; w < 16; ++w) {
      int e = w * 256 + tid;
      int rrel = e >> 6, p = e & 63;
      float ys0 = bounce[rrel * 128 + 2 * p], ys1 = bounce[rrel * 128 + 2 * p + 1];
      int t = t0 + pass * 64 + rrel, pp = jt * 64 + p;
      size_t u32b = (size_t)bb * QR_U32 + (size_t)(h * T_ + t) * 2048 + pp;
      u32 qh = ((const u32*)QRH)[u32b];
      float qe = b2f((u16)(qh & 0xffff));
      float qo = b2f((u16)(qh >> 16));
      float2 c = trig_ct(csA, csB, t, pp);
      float xe = fmaxf(qe * c.x + qo * c.y, 0.0f);
      float xo = fmaxf(qo * c.x - qe * c.y, 0.0f);
      u32 hi = (u32)f2b(ys0 * xe) | ((u32)f2b(ys1 * xo) << 16);
      ((u32*)QRH)[u32b] = hi;
    }
    __syncthreads();
  }
}

// G4b: part[bb][h+4*ks] = xyH[ks-half] @ dec_hi[h][ks-half].  1-term, 64KB dbuf.
// grid(16,2,16): h = z&3, ks = (z>>2)&1, bb = z>>3.
__global__ __launch_bounds__(256) void k_g4b(const u16* __restrict__ xyH,
                                             const u16* __restrict__ dtH,
                                             float* __restrict__ part) {
  GEMM_PRE1D
  int it = blockIdx.x, jt = blockIdx.y;
  int h = blockIdx.z & 3, ks = (blockIdx.z >> 2) & 1, bb = blockIdx.z >> 3;
  int z8 = h + 4 * ks;
  int t0 = it * 128;
  size_t ao = (size_t)bb * QR_E + (size_t)(h * T_ + t0) * NN_;
  size_t bo = (size_t)h * D_ * NN_ + (size_t)jt * 128 * NN_;
  int k0 = ks * 32, k1 = ks * 32 + 32;
  {  // prologue
    stage_t(xyH + ao + k0 * 64, NN_, smd1, wid, lane);
    stage_t(dtH + bo + k0 * 64, NN_, smd1 + 8192, wid, lane);
  }
  for (int kb = k0; kb < k1; ++kb) {
    short* cur = smd1 + ((kb - k0) & 1) * 16384;
    __syncthreads();
    if (kb + 1 < k1) {
      short* nxt = smd1 + ((kb + 1 - k0) & 1) * 16384;
      stage_t(xyH + ao + (kb + 1) * 64, NN_, nxt, wid, lane);
      stage_t(dtH + bo + (kb + 1) * 64, NN_, nxt + 8192, wid, lane);
    }
    mma64x1(cur, cur + 8192, wr, wc, lane, acc);
  }
  __syncthreads();
#pragma unroll
  for (int pass = 0; pass < 2; ++pass) {
    acc_store_half(bounce, acc, pass, wr, wc, lane, false);
    __syncthreads();
    for (int w = 0; w < 32; ++w) {
      int e = w * 256 + tid;
      int row = e >> 7, col = e & 127;
      part[(size_t)bb * SP_F + ((size_t)z8 * T_ + t0 + pass * 64 + row) * 256 + jt * 128 + col] =
          bounce[row * 128 + col];
    }
    __syncthreads();
  }
}

// LN3: 1024 blocks, r in [0,4096): bb = r>>11.
__global__ __launch_bounds__(256) void k_ln3(const float* __restrict__ part, float* __restrict__ x,
                                             u16* __restrict__ xbH, u16* __restrict__ xbL) {
  int lane = threadIdx.x & 63, wid = threadIdx.x >> 6;
  int r = blockIdx.x * 4 + wid;
  int bb = r >> 11, rl = r & 2047;
  const float* P = part + (size_t)bb * SP_F;
  float a0 = 0, a1 = 0, a2 = 0, a3 = 0;
#pragma unroll
  for (int h = 0; h < 8; ++h) {
    float4 u = ((const float4*)(P + ((size_t)h * T_ + rl) * 256))[lane];
    a0 += u.x; a1 += u.y; a2 += u.z; a3 += u.w;
  }
  float m = wsum(a0 + a1 + a2 + a3) * (1.0f / 256.0f);
  float d0 = a0 - m, d1 = a1 - m, d2 = a2 - m, d3 = a3 - m;
  float var = wsum(d0 * d0 + d1 * d1 + d2 * d2 + d3 * d3) * (1.0f / 256.0f);
  float rs = 1.0f / sqrtf(var + 1e-5f);
  float4 xv = ((const float4*)(x + (size_t)r * 256))[lane];
  float s0 = xv.x + d0 * rs, s1 = xv.y + d1 * rs, s2 = xv.z + d2 * rs, s3 = xv.w + d3 * rs;
  float m2 = wsum(s0 + s1 + s2 + s3) * (1.0f / 256.0f);
  float e0 = s0 - m2, e1 = s1 - m2, e2 = s2 - m2, e3 = s3 - m2;
  float var2 = wsum(e0 * e0 + e1 * e1 + e2 * e2 + e3 * e3) * (1.0f / 256.0f);
  float rs2 = 1.0f / sqrtf(var2 + 1e-5f);
  float y0 = e0 * rs2, y1 = e1 * rs2, y2 = e2 * rs2, y3 = e3 * rs2;
  ((float4*)(x + (size_t)r * 256))[lane] = make_float4(y0, y1, y2, y3);
  ushort4 oh, ol;
  oh.x = f2b(y0); ol.x = f2b(y0 - b2f(oh.x));
  oh.y = f2b(y1); ol.y = f2b(y1 - b2f(oh.y));
  oh.z = f2b(y2); ol.z = f2b(y2 - b2f(oh.z));
  oh.w = f2b(y3); ol.w = f2b(y3 - b2f(oh.w));
  ((ushort4*)(xbH + (size_t)r * 256))[lane] = oh;
  ((ushort4*)(xbL + (size_t)r * 256))[lane] = ol;
}

// G5: logits = xb @ lm_head (3-term) -> f32 out.  grid(32,2).
__global__ __launch_bounds__(256) void k_g5(const u16* __restrict__ xbH,
                                            const u16* __restrict__ xbL,
                                            const u16* __restrict__ lmH,
                                            const u16* __restrict__ lmL,
                                            float* __restrict__ out) {
  __shared__ float smf[16384];
  short* AsH = (short*)smf;
  short* AsL = AsH + 8192;
  short* BsH = AsH + 16384;
  short* BsL = AsH + 24576;
  int tid = threadIdx.x;
  int lane = tid & 63, wid = tid >> 6;
  int wr = wid >> 1, wc = wid & 1;
  f4 acc[4][4];
  acc_zero(acc);
  int it = blockIdx.x, jt = blockIdx.y;
  size_t ao = (size_t)it * 128 * 256;
  size_t bo = (size_t)jt * 128 * 256;
  for (int kb = 0; kb < 4; ++kb) {
    stage_t(xbH + ao + kb * 64, 256, AsH, wid, lane);
    stage_t(xbL + ao + kb * 64, 256, AsL, wid, lane);
    stage_t(lmH + bo + kb * 64, 256, BsH, wid, lane);
    stage_t(lmL + bo + kb * 64, 256, BsL, wid, lane);
    __syncthreads();
    mma64x3(AsH, AsL, BsH, BsL, wr, wc, lane, acc);
    __syncthreads();
  }
  acc_store_f32(smf, acc, wr, wc, lane, false);
  __syncthreads();
  for (int w = 0; w < 64; ++w) {
    int e = w * 256 + tid;
    int row = e >> 7, col = e & 127;
    out[(size_t)(it * 128 + row) * 256 + jt * 128 + col] = smf[row * 128 + col];
  }
}

extern "C" void kernel_launch(void* const* d_in, const int* in_sizes, int n_in, void* d_out,
                              int out_size, void* d_ws, size_t ws_size, hipStream_t stream) {
  const int*   idx   = (const int*)d_in[0];
  const float* embed = (const float*)d_in[1];
  const float* enc   = (const float*)d_in[2];
  const float* encv  = (const float*)d_in[3];
  const float* dec   = (const float*)d_in[4];
  const float* lm    = (const float*)d_in[5];

  if (ws_size < WS_NEED) {
    hipMemsetAsync(d_out, 0x46, (size_t)out_size * 4, stream);
    return;
  }

  char* w = (char*)d_ws;
  float2* csA  = (float2*)(w + CSA_OFF);
  float2* csB  = (float2*)(w + CSB_OFF);
  u16*    etH  = (u16*)(w + ETH_OFF);
  u16*    evH  = (u16*)(w + EVH_OFF);
  u16*    dtH  = (u16*)(w + DTH_OFF);
  u16*    lmH  = (u16*)(w + LMH_OFF);
  u16*    lmL  = (u16*)(w + LML_OFF);
  float*  x    = (float*)(w + X_OFF);
  u16*    xbH  = (u16*)(w + XBH_OFF);
  u16*    xbL  = (u16*)(w + XBL_OFF);
  u16*    xbTH = (u16*)(w + XBTH_OFF);
  u16*    QRH  = (u16*)(w + QRH_OFF);
  u16*    SpH  = (u16*)(w + SH_OFF);
  float*  part = (float*)(w + SH_OFF);
  float*  yKV  = (float*)(w + YKV_OFF);
  u16*    ykH  = (u16*)(w + YKH_OFF);

  k_costab<<<1152, 256, 0, stream>>>(csA, csB);
  k_tcast1<<<dim3(128, 8, 4), dim3(32, 8), 0, stream>>>(enc, etH, 256, 4096);
  k_tcast1<<<dim3(128, 8, 4), dim3(32, 8), 0, stream>>>(encv, evH, 256, 4096);
  k_tcast1<<<dim3(8, 128, 4), dim3(32, 8), 0, stream>>>(dec, dtH, 4096, 256);
  k_tcast2<<<dim3(8, 8, 1), dim3(32, 8), 0, stream>>>(lm, lmH, lmL, 256, 256);
  k_ln_embed<<<1024, 256, 0, stream>>>(idx, embed, x, xbH, xbL);
  k_xbt<<<4096, 256, 0, stream>>>(xbH, xbTH);

  for (int l = 0; l < NLAYER; ++l) {
    k_g1<<<dim3(16, 32, 8), 256, 0, stream>>>(xbH, etH, csA, csB, QRH);
    k_g2<<<408, 512, 0, stream>>>(QRH, SpH);
    k_g3<<<dim3(16, 2, 8), 256, 0, stream>>>(SpH, xbTH, yKV);
    k_ln_f32<<<4096, 256, 0, stream>>>(yKV, ykH);
    k_g4a<<<dim3(16, 32, 8), 256, 0, stream>>>(ykH, evH, csA, csB, QRH);
    k_g4b<<<dim3(16, 2, 16), 256, 0, stream>>>(QRH, dtH, part);
    k_ln3<<<1024, 256, 0, stream>>>(part, x, xbH, xbL);
    k_xbt<<<4096, 256, 0, stream>>>(xbH, xbTH);
  }
  k_g5<<<dim3(32, 2), 256, 0, stream>>>(xbH, xbL, lmH, lmL, (float*)d_out);
}

// Round 24
// 3010.529 us; speedup vs baseline: 1.3454x; 1.0283x over previous
//
#include <hip/hip_runtime.h>

// ===== BDH forward on MI355X — R24: exact R21 restore (proven 3022us) =====
// R22 (g2 VGPR spill) and R23 (g1/g4a dbuf occupancy loss) both regressed.
// R24 = R21: batch-parallel, 1-term g1/g2/g3/g4a/g4b (hi operands), g2 row-
// triple 128x384 @ 512 threads 128KB dbuf, g5 3-term, f32 LNs. absmax 0.01367.

typedef unsigned short u16;
typedef unsigned int   u32;
typedef __attribute__((ext_vector_type(8))) short bf8;
typedef __attribute__((ext_vector_type(4))) float f4;

#define T_  2048
#define D_  256
#define NH_ 4
#define NN_ 4096
#define NLAYER 6

// per-batch strides (elements)
#define XB_E   524288u
#define QR_E   33554432u
#define QR_U32 16777216u
#define SP_U32 4456448u
#define SP_F   4456448u
#define YKV_F  2097152u
#define YKH_E  2097152u

// ---- workspace layout (bytes) ----
#define CSA_OFF  ((size_t)0)
#define CSB_OFF  (CSA_OFF  + 262144)
#define ETH_OFF  (CSB_OFF  + 2097152)
#define EVH_OFF  (ETH_OFF  + 8388608)
#define DTH_OFF  (EVH_OFF  + 8388608)
#define LMH_OFF  (DTH_OFF  + 8388608)
#define LML_OFF  (LMH_OFF  + 131072)
#define X_OFF    (LML_OFF  + 131072)
#define XBH_OFF  (X_OFF    + 4194304)
#define XBL_OFF  (XBH_OFF  + 2097152)
#define XBTH_OFF (XBL_OFF  + 2097152)
#define QRH_OFF  (XBTH_OFF + 2097152)
#define SH_OFF   (QRH_OFF  + 134217728)
#define YKV_OFF  (SH_OFF   + 35651584)
#define YKH_OFF  (YKV_OFF  + 16777216)
#define WS_NEED  (YKH_OFF  + 8388608)

// ---------- helpers ----------
__device__ __forceinline__ u16 f2b(float f) {
  u32 u = __builtin_bit_cast(u32, f);
  u32 r = u + 0x7fffu + ((u >> 16) & 1u);
  return (u16)(r >> 16);
}
__device__ __forceinline__ float b2f(u16 h) {
  u32 u = ((u32)h) << 16;
  return __builtin_bit_cast(float, u);
}
__device__ __forceinline__ float wsum(float v) {
#pragma unroll
  for (int o = 32; o; o >>= 1) v += __shfl_xor(v, o, 64);
  return v;
}
__device__ __forceinline__ float2 trig_ct(const float2* csA, const float2* csB, int t, int pp) {
  float2 a = csA[(t >> 7) * 2048 + pp];
  float2 b = csB[(t & 127) * 2048 + pp];
  return make_float2(a.x * b.x - a.y * b.y, a.x * b.y + a.y * b.x);
}
__device__ __forceinline__ void gld16(const u16* g, short* l) {
  __builtin_amdgcn_global_load_lds(
      (const __attribute__((address_space(1))) u32*)g,
      (__attribute__((address_space(3))) u32*)l, 16, 0, 0);
}
// stage 128x64 bf16 tile into LDS [128][64], XOR-swizzled; 256-thread form
__device__ __forceinline__ void stage_t(const u16* g, int lda, short* s, int wid, int lane) {
  int r8 = lane >> 3;
  int c8 = ((lane & 7) ^ r8) * 8;
#pragma unroll
  for (int j = 0; j < 4; ++j) {
    int row = wid * 32 + j * 8;
    gld16(g + (size_t)(row + r8) * lda + c8, s + row * 64);
  }
}
// 512-thread (8-wave) stage
__device__ __forceinline__ void stage_t8(const u16* g, int lda, short* s, int wid, int lane) {
  int r8 = lane >> 3;
  int c8 = ((lane & 7) ^ r8) * 8;
#pragma unroll
  for (int j = 0; j < 2; ++j) {
    int row = wid * 16 + j * 8;
    gld16(g + (size_t)(row + r8) * lda + c8, s + row * 64);
  }
}
// 3-term split: 96 MFMA — g5 only
__device__ __forceinline__ void mma64x3(const short* AsH, const short* AsL, const short* BsH,
                                        const short* BsL, int wr, int wc, int lane,
                                        f4 acc[4][4]) {
  int r15 = lane & 15, hi = lane >> 4;
  int sw = (r15 & 7) << 3;
#pragma unroll
  for (int kk = 0; kk < 2; ++kk) {
    int ko = (kk * 32 + hi * 8) ^ sw;
    bf8 ah[4], al[4], bh[4], bl[4];
#pragma unroll
    for (int m = 0; m < 4; ++m) {
      int off = (wr * 64 + m * 16 + r15) * 64 + ko;
      ah[m] = *(const bf8*)(AsH + off);
      al[m] = *(const bf8*)(AsL + off);
    }
#pragma unroll
    for (int n = 0; n < 4; ++n) {
      int off = (wc * 64 + n * 16 + r15) * 64 + ko;
      bh[n] = *(const bf8*)(BsH + off);
      bl[n] = *(const bf8*)(BsL + off);
    }
#pragma unroll
    for (int m = 0; m < 4; ++m)
#pragma unroll
      for (int n = 0; n < 4; ++n) {
        acc[m][n] = __builtin_amdgcn_mfma_f32_16x16x32_bf16(ah[m], bh[n], acc[m][n], 0, 0, 0);
        acc[m][n] = __builtin_amdgcn_mfma_f32_16x16x32_bf16(al[m], bh[n], acc[m][n], 0, 0, 0);
        acc[m][n] = __builtin_amdgcn_mfma_f32_16x16x32_bf16(ah[m], bl[n], acc[m][n], 0, 0, 0);
      }
  }
}
// 1-term: 32 MFMA — g1/g3/g4a/g4b
__device__ __forceinline__ void mma64x1(const short* AsH, const short* BsH,
                                        int wr, int wc, int lane, f4 acc[4][4]) {
  int r15 = lane & 15, hi = lane >> 4;
  int sw = (r15 & 7) << 3;
#pragma unroll
  for (int kk = 0; kk < 2; ++kk) {
    int ko = (kk * 32 + hi * 8) ^ sw;
    bf8 ah[4], bh[4];
#pragma unroll
    for (int m = 0; m < 4; ++m)
      ah[m] = *(const bf8*)(AsH + (wr * 64 + m * 16 + r15) * 64 + ko);
#pragma unroll
    for (int n = 0; n < 4; ++n)
      bh[n] = *(const bf8*)(BsH + (wc * 64 + n * 16 + r15) * 64 + ko);
#pragma unroll
    for (int m = 0; m < 4; ++m)
#pragma unroll
      for (int n = 0; n < 4; ++n)
        acc[m][n] = __builtin_amdgcn_mfma_f32_16x16x32_bf16(ah[m], bh[n], acc[m][n], 0, 0, 0);
  }
}
__device__ __forceinline__ void acc_zero(f4 acc[4][4]) {
#pragma unroll
  for (int m = 0; m < 4; ++m)
#pragma unroll
    for (int n = 0; n < 4; ++n)
#pragma unroll
      for (int j = 0; j < 4; ++j) acc[m][n][j] = 0.0f;
}
__device__ __forceinline__ void acc_store_f32(float* F, f4 acc[4][4], int wr, int wc, int lane,
                                              bool relu) {
  int r15 = lane & 15, q = lane >> 4;
#pragma unroll
  for (int m = 0; m < 4; ++m)
#pragma unroll
    for (int n = 0; n < 4; ++n)
#pragma unroll
      for (int j = 0; j < 4; ++j) {
        float v = acc[m][n][j];
        if (relu) v = fmaxf(v, 0.0f);
        F[(wr * 64 + m * 16 + q * 4 + j) * 128 + wc * 64 + n * 16 + r15] = v;
      }
}
__device__ __forceinline__ void acc_store_half(float* F, f4 acc[4][4], int pass, int wr, int wc,
                                               int lane, bool relu) {
  if (wr != pass) return;
  int r15 = lane & 15, q = lane >> 4;
#pragma unroll
  for (int m = 0; m < 4; ++m)
#pragma unroll
    for (int n = 0; n < 4; ++n)
#pragma unroll
      for (int j = 0; j < 4; ++j) {
        float v = acc[m][n][j];
        if (relu) v = fmaxf(v, 0.0f);
        F[(m * 16 + q * 4 + j) * 128 + wc * 64 + n * 16 + r15] = v;
      }
}

// ---------- prep kernels ----------
__global__ __launch_bounds__(256) void k_costab(float2* csA, float2* csB) {
  int id = blockIdx.x * 256 + threadIdx.x;
  int r = id >> 11, p = id & 2047;
  double freq = exp2(-(double)p / 128.0) * 0.15915494309189533577;
  int t = (r < 16) ? (r * 128) : (r - 16);
  double ph = fmod((double)t * freq, 1.0);
  double ang = ph * 6.2831853071795864769;
  float2 v = make_float2((float)cos(ang), (float)sin(ang));
  if (r < 16) csA[r * 2048 + p] = v;
  else        csB[(r - 16) * 2048 + p] = v;
}

__global__ __launch_bounds__(256) void k_tcast1(const float* __restrict__ in,
                                                u16* __restrict__ outH, int R, int C) {
  __shared__ float tl[32][33];
  size_t bo = (size_t)blockIdx.z * R * C;
  int tx = threadIdx.x, ty = threadIdx.y;
  int c = blockIdx.x * 32 + tx, r0 = blockIdx.y * 32 + ty;
#pragma unroll
  for (int k = 0; k < 32; k += 8) tl[ty + k][tx] = in[bo + (size_t)(r0 + k) * C + c];
  __syncthreads();
  int rr = blockIdx.y * 32 + tx, cc0 = blockIdx.x * 32 + ty;
#pragma unroll
  for (int k = 0; k < 32; k += 8) outH[bo + (size_t)(cc0 + k) * R + rr] = f2b(tl[tx][ty + k]);
}

__global__ __launch_bounds__(256) void k_tcast2(const float* __restrict__ in,
                                                u16* __restrict__ outH, u16* __restrict__ outL,
                                                int R, int C) {
  __shared__ float tl[32][33];
  int tx = threadIdx.x, ty = threadIdx.y;
  int c = blockIdx.x * 32 + tx, r0 = blockIdx.y * 32 + ty;
#pragma unroll
  for (int k = 0; k < 32; k += 8) tl[ty + k][tx] = in[(size_t)(r0 + k) * C + c];
  __syncthreads();
  int rr = blockIdx.y * 32 + tx, cc0 = blockIdx.x * 32 + ty;
#pragma unroll
  for (int k = 0; k < 32; k += 8) {
    float v = tl[tx][ty + k];
    u16 h = f2b(v);
    outH[(size_t)(cc0 + k) * R + rr] = h;
    outL[(size_t)(cc0 + k) * R + rr] = f2b(v - b2f(h));
  }
}

__global__ __launch_bounds__(256) void k_ln_embed(const int* __restrict__ idx,
                                                  const float* __restrict__ embed,
                                                  float* __restrict__ x, u16* __restrict__ xbH,
                                                  u16* __restrict__ xbL) {
  int lane = threadIdx.x & 63, wid = threadIdx.x >> 6;
  int r = blockIdx.x * 4 + wid;
  int id = idx[r] & 255;
  float4 v = ((const float4*)(embed + (size_t)id * 256))[lane];
  float m = wsum(v.x + v.y + v.z + v.w) * (1.0f / 256.0f);
  float d0 = v.x - m, d1 = v.y - m, d2 = v.z - m, d3 = v.w - m;
  float var = wsum(d0 * d0 + d1 * d1 + d2 * d2 + d3 * d3) * (1.0f / 256.0f);
  float rs = 1.0f / sqrtf(var + 1e-5f);
  float y0 = d0 * rs, y1 = d1 * rs, y2 = d2 * rs, y3 = d3 * rs;
  ((float4*)(x + (size_t)r * 256))[lane] = make_float4(y0, y1, y2, y3);
  ushort4 oh, ol;
  oh.x = f2b(y0); ol.x = f2b(y0 - b2f(oh.x));
  oh.y = f2b(y1); ol.y = f2b(y1 - b2f(oh.y));
  oh.z = f2b(y2); ol.z = f2b(y2 - b2f(oh.z));
  oh.w = f2b(y3); ol.w = f2b(y3 - b2f(oh.w));
  ((ushort4*)(xbH + (size_t)r * 256))[lane] = oh;
  ((ushort4*)(xbL + (size_t)r * 256))[lane] = ol;
}

__global__ __launch_bounds__(256) void k_xbt(const u16* __restrict__ xbH,
                                             u16* __restrict__ xbTH) {
  int id = blockIdx.x * 256 + threadIdx.x;
  int b = id >> 19;
  int w19 = id & 524287;
  int t = w19 & 2047, d = w19 >> 11;
  xbTH[id] = xbH[(size_t)b * XB_E + (size_t)t * 256 + d];
}

// ---------- GEMM kernels ----------
// 32KB single-buffer preamble (g1/g4a): 2 tiles; bounce aliases same 32KB
#define GEMM_PRE1                                                       \
  __shared__ short sm1[16384];                                          \
  short* T0 = sm1;                                                      \
  short* T1 = sm1 + 8192;                                               \
  float* bounce = (float*)sm1;                                          \
  int tid = threadIdx.x;                                                \
  int lane = tid & 63, wid = tid >> 6;                                  \
  int wr = wid >> 1, wc = wid & 1;                                      \
  f4 acc[4][4];                                                         \
  acc_zero(acc);

// 64KB double-buffer preamble (g3/g4b)
#define GEMM_PRE1D                                                      \
  __shared__ short smd1[32768];                                         \
  float* bounce = (float*)smd1;                                         \
  int tid = threadIdx.x;                                                \
  int lane = tid & 63, wid = tid >> 6;                                  \
  int wr = wid >> 1, wc = wid & 1;                                      \
  f4 acc[4][4];                                                         \
  acc_zero(acc);

// G1: x_sparse=relu(xbH@enc_hi[h]) -> rope -> QR hi.  grid(16,32,8): z = bb*4+h.
__global__ __launch_bounds__(256) void k_g1(const u16* __restrict__ xbH,
                                            const u16* __restrict__ etH,
                                            const float2* __restrict__ csA,
                                            const float2* __restrict__ csB,
                                            u16* __restrict__ QRH) {
  GEMM_PRE1
  int it = blockIdx.x, jt = blockIdx.y;
  int h = blockIdx.z & 3, bb = blockIdx.z >> 2;
  size_t ao = (size_t)bb * XB_E + (size_t)it * 128 * 256;
  size_t bo = (size_t)h * NN_ * 256 + (size_t)jt * 128 * 256;
  for (int kb = 0; kb < 4; ++kb) {
    stage_t(xbH + ao + kb * 64, 256, T0, wid, lane);
    stage_t(etH + bo + kb * 64, 256, T1, wid, lane);
    __syncthreads();
    mma64x1(T0, T1, wr, wc, lane, acc);
    __syncthreads();
  }
#pragma unroll
  for (int pass = 0; pass < 2; ++pass) {
    acc_store_half(bounce, acc, pass, wr, wc, lane, true);
    __syncthreads();
    for (int w = 0; w < 16; ++w) {
      int e = w * 256 + tid;
      int rrel = e >> 6, p = e & 63;
      float v0 = bounce[rrel * 128 + 2 * p], v1 = bounce[rrel * 128 + 2 * p + 1];
      int t = it * 128 + pass * 64 + rrel, pp = jt * 64 + p;
      float2 c = trig_ct(csA, csB, t, pp);
      float q0 = v0 * c.x - v1 * c.y;
      float q1 = v1 * c.x + v0 * c.y;
      u32 hi = (u32)f2b(q0) | ((u32)f2b(q1) << 16);
      ((u32*)QRH)[(size_t)bb * QR_U32 + (size_t)(h * T_ + t) * 2048 + pp] = hi;
    }
    __syncthreads();
  }
}

// G2: S = mask(Qh@Qh^T), 1-term, row-triple, 512 threads, 128KB dbuf.
// grid 408 = 8 XCDs x 51 (bijective chunk); lb -> (bb, h, triple).
__global__ __launch_bounds__(512) void k_g2(const u16* __restrict__ QRH,
                                            u16* __restrict__ SpH) {
  __shared__ short smp[65536];             // 128KB: 2 x (AsH|B0|B1|B2)
  float* bounce = (float*)smp;
  int tid = threadIdx.x;
  int lane = tid & 63, wid = tid >> 6;
  int wr = wid >> 2, wc = wid & 3;         // 2 row-halves x 4 col-waves (64x96)
  f4 acc[4][6];
#pragma unroll
  for (int m = 0; m < 4; ++m)
#pragma unroll
    for (int n = 0; n < 6; ++n)
#pragma unroll
      for (int j = 0; j < 4; ++j) acc[m][n][j] = 0.0f;
  int orig = blockIdx.x;
  int lb = (orig & 7) * 51 + (orig >> 3);  // 408 = 8*51 exact chunk
  int bb = lb / 204;
  int l2 = lb % 204;
  int h = l2 / 51;
  int rem = l2 % 51, i = 0;
  while (rem >= (i + 3) / 3) { rem -= (i + 3) / 3; ++i; }
  int j0 = rem * 3, j1 = j0 + 1, j2 = j0 + 2;
  bool has1 = (j1 <= i), has2 = (j2 <= i);
  size_t base = (size_t)bb * QR_E + (size_t)h * T_ * NN_;
  size_t ao = base + (size_t)i * 128 * NN_;
  size_t bo0 = base + (size_t)j0 * 128 * NN_;
  size_t bo1 = base + (size_t)j1 * 128 * NN_;
  size_t bo2 = base + (size_t)j2 * 128 * NN_;
  {  // prologue: stage k=0 into buf0
    stage_t8(QRH + ao, NN_, smp, wid, lane);
    stage_t8(QRH + bo0, NN_, smp + 8192, wid, lane);
    if (has1) stage_t8(QRH + bo1, NN_, smp + 16384, wid, lane);
    if (has2) stage_t8(QRH + bo2, NN_, smp + 24576, wid, lane);
  }
  int r15 = lane & 15, hi4 = lane >> 4;
  int sw = (r15 & 7) << 3;
  for (int kb = 0; kb < 64; ++kb) {
    short* cur = smp + (kb & 1) * 32768;
    __syncthreads();
    if (kb + 1 < 64) {
      short* nxt = smp + ((kb + 1) & 1) * 32768;
      stage_t8(QRH + ao + (kb + 1) * 64, NN_, nxt, wid, lane);
      stage_t8(QRH + bo0 + (kb + 1) * 64, NN_, nxt + 8192, wid, lane);
      if (has1) stage_t8(QRH + bo1 + (kb + 1) * 64, NN_, nxt + 16384, wid, lane);
      if (has2) stage_t8(QRH + bo2 + (kb + 1) * 64, NN_, nxt + 24576, wid, lane);
    }
#pragma unroll
    for (int kk = 0; kk < 2; ++kk) {
      int ko = (kk * 32 + hi4 * 8) ^ sw;
      bf8 ah[4];
#pragma unroll
      for (int m = 0; m < 4; ++m)
        ah[m] = *(const bf8*)(cur + (wr * 64 + m * 16 + r15) * 64 + ko);
#pragma unroll
      for (int n = 0; n < 6; ++n) {
        int cn = wc * 96 + n * 16;
        int bp = cn >> 7;
        if (bp == 1 && !has1) continue;
        if (bp == 2 && !has2) continue;
        bf8 bh = *(const bf8*)(cur + 8192 + bp * 8192 + ((cn & 127) + r15) * 64 + ko);
#pragma unroll
        for (int m = 0; m < 4; ++m)
          acc[m][n] = __builtin_amdgcn_mfma_f32_16x16x32_bf16(ah[m], bh, acc[m][n], 0, 0, 0);
      }
    }
  }
  __syncthreads();
  int q4 = lane >> 4;
#pragma unroll
  for (int jb = 0; jb < 3; ++jb) {
    if (jb == 1 && !has1) break;
    if (jb == 2 && !has2) break;
    int j = j0 + jb;
    size_t dblk = ((size_t)h * 136 + (size_t)i * (i + 1) / 2 + j) * 16384;
    bool diag = (i == j);
#pragma unroll
    for (int pass = 0; pass < 2; ++pass) {
      if (wr == pass) {
#pragma unroll
        for (int m = 0; m < 4; ++m)
#pragma unroll
          for (int n = 0; n < 6; ++n) {
            int cn = wc * 96 + n * 16;
            if ((cn >> 7) != jb) continue;
#pragma unroll
            for (int jj = 0; jj < 4; ++jj)
              bounce[(m * 16 + q4 * 4 + jj) * 128 + (cn & 127) + r15] = acc[m][n][jj];
          }
      }
      __syncthreads();
      for (int w = 0; w < 8; ++w) {
        int e = w * 512 + tid;
        int rrel = e >> 6, p = e & 63;
        int row = pass * 64 + rrel;
        float s0 = bounce[rrel * 128 + 2 * p], s1 = bounce[rrel * 128 + 2 * p + 1];
        if (diag) {  // strictly lower: col < row
          if (2 * p >= row) s0 = 0.0f;
          if (2 * p + 1 >= row) s1 = 0.0f;
        }
        u32 hi = (u32)f2b(s0) | ((u32)f2b(s1) << 16);
        ((u32*)SpH)[(size_t)bb * SP_U32 + (dblk >> 1) + row * 64 + p] = hi;
      }
      __syncthreads();
    }
  }
}

// G3: yKV = S_hi @ xbTH, 1-term, full K, 64KB dbuf.  grid(16,2,8): z = bb*4+h.
__global__ __launch_bounds__(256) void k_g3(const u16* __restrict__ SpH,
                                            const u16* __restrict__ xbTH,
                                            float* __restrict__ yKV) {
  GEMM_PRE1D
  int i = blockIdx.x, jt = blockIdx.y;
  int h = blockIdx.z & 3, bb = blockIdx.z >> 2;
  size_t tri = (size_t)bb * 544 + (size_t)h * 136 + (size_t)i * (i + 1) / 2;
  size_t bo = (size_t)bb * XB_E + (size_t)jt * 128 * T_;
  int nk = 2 * (i + 1);
  {  // prologue
    stage_t(SpH + tri * 16384, 128, smd1, wid, lane);
    stage_t(xbTH + bo, T_, smd1 + 8192, wid, lane);
  }
  for (int kb = 0; kb < nk; ++kb) {
    short* cur = smd1 + (kb & 1) * 16384;
    __syncthreads();
    if (kb + 1 < nk) {
      short* nxt = smd1 + ((kb + 1) & 1) * 16384;
      size_t aoff = (tri + ((kb + 1) >> 1)) * 16384 + ((kb + 1) & 1) * 64;
      stage_t(SpH + aoff, 128, nxt, wid, lane);
      stage_t(xbTH + bo + (kb + 1) * 64, T_, nxt + 8192, wid, lane);
    }
    mma64x1(cur, cur + 8192, wr, wc, lane, acc);
  }
  __syncthreads();
#pragma unroll
  for (int pass = 0; pass < 2; ++pass) {
    acc_store_half(bounce, acc, pass, wr, wc, lane, false);
    __syncthreads();
    for (int w = 0; w < 32; ++w) {
      int e = w * 256 + tid;
      int row = e >> 7, col = e & 127;
      yKV[(size_t)bb * YKV_F + ((size_t)h * T_ + i * 128 + pass * 64 + row) * 256 + jt * 128 + col] =
          bounce[row * 128 + col];
    }
    __syncthreads();
  }
}

// LN over f32 rows of 256 -> hi bf16.  4096 blocks.
__global__ __launch_bounds__(256) void k_ln_f32(const float* __restrict__ in,
                                                u16* __restrict__ outH) {
  int lane = threadIdx.x & 63, wid = threadIdx.x >> 6;
  int r = blockIdx.x * 4 + wid;
  float4 v = ((const float4*)(in + (size_t)r * 256))[lane];
  float m = wsum(v.x + v.y + v.z + v.w) * (1.0f / 256.0f);
  float d0 = v.x - m, d1 = v.y - m, d2 = v.z - m, d3 = v.w - m;
  float var = wsum(d0 * d0 + d1 * d1 + d2 * d2 + d3 * d3) * (1.0f / 256.0f);
  float rs = 1.0f / sqrtf(var + 1e-5f);
  ushort4 oh;
  oh.x = f2b(d0 * rs); oh.y = f2b(d1 * rs); oh.z = f2b(d2 * rs); oh.w = f2b(d3 * rs);
  ((ushort4*)(outH + (size_t)r * 256))[lane] = oh;
}

// G4a: y_sparse=relu(ykH@encv_hi[h]); gate by invrope(QR hi); xy -> QR hi.
// grid(16,32,8): z = bb*4+h.
__global__ __launch_bounds__(256) void k_g4a(const u16* __restrict__ ykH,
                                             const u16* __restrict__ evH,
                                             const float2* __restrict__ csA,
                                             const float2* __restrict__ csB,
                                             u16* __restrict__ QRH) {
  GEMM_PRE1
  int it = blockIdx.x, jt = blockIdx.y;
  int h = blockIdx.z & 3, bb = blockIdx.z >> 2;
  int t0 = it * 128;
  size_t ao = (size_t)bb * YKH_E + (size_t)(h * T_ + t0) * 256;
  size_t bo = (size_t)h * NN_ * 256 + (size_t)jt * 128 * 256;
  for (int kb = 0; kb < 4; ++kb) {
    stage_t(ykH + ao + kb * 64, 256, T0, wid, lane);
    stage_t(evH + bo + kb * 64, 256, T1, wid, lane);
    __syncthreads();
    mma64x1(T0, T1, wr, wc, lane, acc);
    __syncthreads();
  }
#pragma unroll
  for (int pass = 0; pass < 2; ++pass) {
    acc_store_half(bounce, acc, pass, wr, wc, lane, true);
    __syncthreads();
    for (int w = 0; w < 16; ++w) {
      int e = w * 256 + tid;
      int rrel = e >> 6, p = e & 63;
      float ys0 = bounce[rrel * 128 + 2 * p], ys1 = bounce[rrel * 128 + 2 * p + 1];
      int t = t0 + pass * 64 + rrel, pp = jt * 64 + p;
      size_t u32b = (size_t)bb * QR_U32 + (size_t)(h * T_ + t) * 2048 + pp;
      u32 qh = ((const u32*)QRH)[u32b];
      float qe = b2f((u16)(qh & 0xffff));
      float qo = b2f((u16)(qh >> 16));
      float2 c = trig_ct(csA, csB, t, pp);
      float xe = fmaxf(qe * c.x + qo * c.y, 0.0f);
      float xo = fmaxf(qo * c.x - qe * c.y, 0.0f);
      u32 hi = (u32)f2b(ys0 * xe) | ((u32)f2b(ys1 * xo) << 16);
      ((u32*)QRH)[u32b] = hi;
    }
    __syncthreads();
  }
}

// G4b: part[bb][h+4*ks] = xyH[ks-half] @ dec_hi[h][ks-half].  1-term, 64KB dbuf.
// grid(16,2,16): h = z&3, ks = (z>>2)&1, bb = z>>3.
__global__ __launch_bounds__(256) void k_g4b(const u16* __restrict__ xyH,
                                             const u16* __restrict__ dtH,
                                             float* __restrict__ part) {
  GEMM_PRE1D
  int it = blockIdx.x, jt = blockIdx.y;
  int h = blockIdx.z & 3, ks = (blockIdx.z >> 2) & 1, bb = blockIdx.z >> 3;
  int z8 = h + 4 * ks;
  int t0 = it * 128;
  size_t ao = (size_t)bb * QR_E + (size_t)(h * T_ + t0) * NN_;
  size_t bo = (size_t)h * D_ * NN_ + (size_t)jt * 128 * NN_;
  int k0 = ks * 32, k1 = ks * 32 + 32;
  {  // prologue
    stage_t(xyH + ao + k0 * 64, NN_, smd1, wid, lane);
    stage_t(dtH + bo + k0 * 64, NN_, smd1 + 8192, wid, lane);
  }
  for (int kb = k0; kb < k1; ++kb) {
    short* cur = smd1 + ((kb - k0) & 1) * 16384;
    __syncthreads();
    if (kb + 1 < k1) {
      short* nxt = smd1 + ((kb + 1 - k0) & 1) * 16384;
      stage_t(xyH + ao + (kb + 1) * 64, NN_, nxt, wid, lane);
      stage_t(dtH + bo + (kb + 1) * 64, NN_, nxt + 8192, wid, lane);
    }
    mma64x1(cur, cur + 8192, wr, wc, lane, acc);
  }
  __syncthreads();
#pragma unroll
  for (int pass = 0; pass < 2; ++pass) {
    acc_store_half(bounce, acc, pass, wr, wc, lane, false);
    __syncthreads();
    for (int w = 0; w < 32; ++w) {
      int e = w * 256 + tid;
      int row = e >> 7, col = e & 127;
      part[(size_t)bb * SP_F + ((size_t)z8 * T_ + t0 + pass * 64 + row) * 256 + jt * 128 + col] =
          bounce[row * 128 + col];
    }
    __syncthreads();
  }
}

// LN3: 1024 blocks, r in [0,4096): bb = r>>11.
__global__ __launch_bounds__(256) void k_ln3(const float* __restrict__ part, float* __restrict__ x,
                                             u16* __restrict__ xbH, u16* __restrict__ xbL) {
  int lane = threadIdx.x & 63, wid = threadIdx.x >> 6;
  int r = blockIdx.x * 4 + wid;
  int bb = r >> 11, rl = r & 2047;
  const float* P = part + (size_t)bb * SP_F;
  float a0 = 0, a1 = 0, a2 = 0, a3 = 0;
#pragma unroll
  for (int h = 0; h < 8; ++h) {
    float4 u = ((const float4*)(P + ((size_t)h * T_ + rl) * 256))[lane];
    a0 += u.x; a1 += u.y; a2 += u.z; a3 += u.w;
  }
  float m = wsum(a0 + a1 + a2 + a3) * (1.0f / 256.0f);
  float d0 = a0 - m, d1 = a1 - m, d2 = a2 - m, d3 = a3 - m;
  float var = wsum(d0 * d0 + d1 * d1 + d2 * d2 + d3 * d3) * (1.0f / 256.0f);
  float rs = 1.0f / sqrtf(var + 1e-5f);
  float4 xv = ((const float4*)(x + (size_t)r * 256))[lane];
  float s0 = xv.x + d0 * rs, s1 = xv.y + d1 * rs, s2 = xv.z + d2 * rs, s3 = xv.w + d3 * rs;
  float m2 = wsum(s0 + s1 + s2 + s3) * (1.0f / 256.0f);
  float e0 = s0 - m2, e1 = s1 - m2, e2 = s2 - m2, e3 = s3 - m2;
  float var2 = wsum(e0 * e0 + e1 * e1 + e2 * e2 + e3 * e3) * (1.0f / 256.0f);
  float rs2 = 1.0f / sqrtf(var2 + 1e-5f);
  float y0 = e0 * rs2, y1 = e1 * rs2, y2 = e2 * rs2, y3 = e3 * rs2;
  ((float4*)(x + (size_t)r * 256))[lane] = make_float4(y0, y1, y2, y3);
  ushort4 oh, ol;
  oh.x = f2b(y0); ol.x = f2b(y0 - b2f(oh.x));
  oh.y = f2b(y1); ol.y = f2b(y1 - b2f(oh.y));
  oh.z = f2b(y2); ol.z = f2b(y2 - b2f(oh.z));
  oh.w = f2b(y3); ol.w = f2b(y3 - b2f(oh.w));
  ((ushort4*)(xbH + (size_t)r * 256))[lane] = oh;
  ((ushort4*)(xbL + (size_t)r * 256))[lane] = ol;
}

// G5: logits = xb @ lm_head (3-term) -> f32 out.  grid(32,2).
__global__ __launch_bounds__(256) void k_g5(const u16* __restrict__ xbH,
                                            const u16* __restrict__ xbL,
                                            const u16* __restrict__ lmH,
                                            const u16* __restrict__ lmL,
                                            float* __restrict__ out) {
  __shared__ float smf[16384];
  short* AsH = (short*)smf;
  short* AsL = AsH + 8192;
  short* BsH = AsH + 16384;
  short* BsL = AsH + 24576;
  int tid = threadIdx.x;
  int lane = tid & 63, wid = tid >> 6;
  int wr = wid >> 1, wc = wid & 1;
  f4 acc[4][4];
  acc_zero(acc);
  int it = blockIdx.x, jt = blockIdx.y;
  size_t ao = (size_t)it * 128 * 256;
  size_t bo = (size_t)jt * 128 * 256;
  for (int kb = 0; kb < 4; ++kb) {
    stage_t(xbH + ao + kb * 64, 256, AsH, wid, lane);
    stage_t(xbL + ao + kb * 64, 256, AsL, wid, lane);
    stage_t(lmH + bo + kb * 64, 256, BsH, wid, lane);
    stage_t(lmL + bo + kb * 64, 256, BsL, wid, lane);
    __syncthreads();
    mma64x3(AsH, AsL, BsH, BsL, wr, wc, lane, acc);
    __syncthreads();
  }
  acc_store_f32(smf, acc, wr, wc, lane, false);
  __syncthreads();
  for (int w = 0; w < 64; ++w) {
    int e = w * 256 + tid;
    int row = e >> 7, col = e & 127;
    out[(size_t)(it * 128 + row) * 256 + jt * 128 + col] = smf[row * 128 + col];
  }
}

extern "C" void kernel_launch(void* const* d_in, const int* in_sizes, int n_in, void* d_out,
                              int out_size, void* d_ws, size_t ws_size, hipStream_t stream) {
  const int*   idx   = (const int*)d_in[0];
  const float* embed = (const float*)d_in[1];
  const float* enc   = (const float*)d_in[2];
  const float* encv  = (const float*)d_in[3];
  const float* dec   = (const float*)d_in[4];
  const float* lm    = (const float*)d_in[5];

  if (ws_size < WS_NEED) {
    hipMemsetAsync(d_out, 0x46, (size_t)out_size * 4, stream);
    return;
  }

  char* w = (char*)d_ws;
  float2* csA  = (float2*)(w + CSA_OFF);
  float2* csB  = (float2*)(w + CSB_OFF);
  u16*    etH  = (u16*)(w + ETH_OFF);
  u16*    evH  = (u16*)(w + EVH_OFF);
  u16*    dtH  = (u16*)(w + DTH_OFF);
  u16*    lmH  = (u16*)(w + LMH_OFF);
  u16*    lmL  = (u16*)(w + LML_OFF);
  float*  x    = (float*)(w + X_OFF);
  u16*    xbH  = (u16*)(w + XBH_OFF);
  u16*    xbL  = (u16*)(w + XBL_OFF);
  u16*    xbTH = (u16*)(w + XBTH_OFF);
  u16*    QRH  = (u16*)(w + QRH_OFF);
  u16*    SpH  = (u16*)(w + SH_OFF);
  float*  part = (float*)(w + SH_OFF);
  float*  yKV  = (float*)(w + YKV_OFF);
  u16*    ykH  = (u16*)(w + YKH_OFF);

  k_costab<<<1152, 256, 0, stream>>>(csA, csB);
  k_tcast1<<<dim3(128, 8, 4), dim3(32, 8), 0, stream>>>(enc, etH, 256, 4096);
  k_tcast1<<<dim3(128, 8, 4), dim3(32, 8), 0, stream>>>(encv, evH, 256, 4096);
  k_tcast1<<<dim3(8, 128, 4), dim3(32, 8), 0, stream>>>(dec, dtH, 4096, 256);
  k_tcast2<<<dim3(8, 8, 1), dim3(32, 8), 0, stream>>>(lm, lmH, lmL, 256, 256);
  k_ln_embed<<<1024, 256, 0, stream>>>(idx, embed, x, xbH, xbL);
  k_xbt<<<4096, 256, 0, stream>>>(xbH, xbTH);

  for (int l = 0; l < NLAYER; ++l) {
    k_g1<<<dim3(16, 32, 8), 256, 0, stream>>>(xbH, etH, csA, csB, QRH);
    k_g2<<<408, 512, 0, stream>>>(QRH, SpH);
    k_g3<<<dim3(16, 2, 8), 256, 0, stream>>>(SpH, xbTH, yKV);
    k_ln_f32<<<4096, 256, 0, stream>>>(yKV, ykH);
    k_g4a<<<dim3(16, 32, 8), 256, 0, stream>>>(ykH, evH, csA, csB, QRH);
    k_g4b<<<dim3(16, 2, 16), 256, 0, stream>>>(QRH, dtH, part);
    k_ln3<<<1024, 256, 0, stream>>>(part, x, xbH, xbL);
    k_xbt<<<4096, 256, 0, stream>>>(xbH, xbTH);
  }
  k_g5<<<dim3(32, 2), 256, 0, stream>>>(xbH, xbL, lmH, lmL, (float*)d_out);
}